// Round 1
// baseline (1004.647 us; speedup 1.0000x reference)
//
#include <hip/hip_runtime.h>
#include <hip/hip_bf16.h>

#define EPS 1e-5f

__device__ __forceinline__ float hsw(float x){
    float t = fminf(fmaxf(x + 3.f, 0.f), 6.f);
    return x * t * (1.f/6.f);
}
__device__ __forceinline__ float sigm(float x){ return 1.f/(1.f + expf(-x)); }

// K1: view_pre[n,c,t] = sum_v Wv[v]*x[n,c,t,v]; time partials over t-chunks.
// x[n,c,t,v] = x0[n, c', t, v'] with s=shift_in[v*64+c], c'=s&63, v'=s>>6.
__global__ __launch_bounds__(256) void k1_viewtime(
    const float* __restrict__ x0, const int* __restrict__ shift_in,
    const float* __restrict__ Wv, const float* __restrict__ Wt,
    float* __restrict__ view_pre, float* __restrict__ time_part,
    float* __restrict__ view_part)
{
    const int n = blockIdx.y, tc = blockIdx.x, t0 = tc*10;
    const int tid = threadIdx.x, c = tid & 63, vg = tid >> 6;
    const float* xn = x0 + n*480000;
    int off[7]; float wv[7]; float tacc[7];
    #pragma unroll
    for (int k=0;k<7;k++){
        int v = vg + 4*k; tacc[k]=0.f;
        if (v < 25){
            int s = shift_in[v*64 + c];
            off[k] = (s & 63)*7500 + (s >> 6);
            wv[k] = Wv[v];
        } else { off[k]=0; wv[k]=0.f; }
    }
    __shared__ float red[4][64];
    float vsum = 0.f, vssq = 0.f;
    for (int tt=0; tt<10; tt++){
        int t = t0 + tt;
        float wt = Wt[t];
        float part = 0.f;
        #pragma unroll
        for (int k=0;k<7;k++){
            int v = vg + 4*k;
            if (v < 25){
                float xval = xn[off[k] + t*25];
                part += wv[k]*xval;
                tacc[k] += wt*xval;
            }
        }
        red[vg][c] = part;
        __syncthreads();
        if (vg == 0){
            float tot = red[0][c]+red[1][c]+red[2][c]+red[3][c];
            view_pre[n*19200 + c*300 + t] = tot;
            vsum += tot; vssq += tot*tot;
        }
        __syncthreads();
    }
    #pragma unroll
    for (int k=0;k<7;k++){
        int v = vg + 4*k;
        if (v < 25) time_part[n*48000 + tc*1600 + c*25 + v] = tacc[k];
    }
    if (vg == 0){
        #pragma unroll
        for (int o=32;o>0;o>>=1){ vsum += __shfl_down(vsum,o); vssq += __shfl_down(vssq,o); }
        if (c == 0){ int b = n*30 + tc; view_part[2*b] = vsum; view_part[2*b+1] = vssq; }
    }
}

// K2a: reduce time partials over 30 chunks -> time_pre; block stat partials.
__global__ __launch_bounds__(256) void k2a_timereduce(
    const float* __restrict__ time_part, float* __restrict__ time_pre,
    float* __restrict__ tstat_part)
{
    int g = blockIdx.x*256 + threadIdx.x;   // [0, 102400)
    int n = g / 1600, r = g % 1600;
    float s = 0.f;
    for (int tc=0; tc<30; tc++) s += time_part[n*48000 + tc*1600 + r];
    time_pre[g] = s;
    float a = s, b = s*s;
    __shared__ float ls[8];
    #pragma unroll
    for (int o=32;o>0;o>>=1){ a += __shfl_down(a,o); b += __shfl_down(b,o); }
    int wid = threadIdx.x >> 6;
    if ((threadIdx.x & 63) == 0){ ls[wid*2] = a; ls[wid*2+1] = b; }
    __syncthreads();
    if (threadIdx.x == 0){
        tstat_part[blockIdx.x*2]   = ls[0]+ls[2]+ls[4]+ls[6];
        tstat_part[blockIdx.x*2+1] = ls[1]+ls[3]+ls[5]+ls[7];
    }
}

// K2b: final scalar BN stats for view/time branches.
__global__ __launch_bounds__(256) void k2b_finstats(
    const float* __restrict__ view_part, const float* __restrict__ tstat_part,
    float* __restrict__ fin)
{
    float acc[4] = {0.f,0.f,0.f,0.f};
    for (int i=threadIdx.x; i<1920; i+=256){ acc[0] += view_part[2*i]; acc[1] += view_part[2*i+1]; }
    for (int i=threadIdx.x; i<400;  i+=256){ acc[2] += tstat_part[2*i]; acc[3] += tstat_part[2*i+1]; }
    __shared__ float ls[4][4];
    int wid = threadIdx.x>>6, lane = threadIdx.x&63;
    #pragma unroll
    for (int j=0;j<4;j++){
        float a = acc[j];
        #pragma unroll
        for (int o=32;o>0;o>>=1) a += __shfl_down(a,o);
        if (lane==0) ls[j][wid] = a;
    }
    __syncthreads();
    if (threadIdx.x==0){
        float VS=ls[0][0]+ls[0][1]+ls[0][2]+ls[0][3];
        float VQ=ls[1][0]+ls[1][1]+ls[1][2]+ls[1][3];
        float TS=ls[2][0]+ls[2][1]+ls[2][2]+ls[2][3];
        float TQ=ls[3][0]+ls[3][1]+ls[3][2]+ls[3][3];
        float vm = VS / 1228800.f;
        float vvar = fmaxf(VQ/1228800.f - vm*vm, 0.f);
        float tm = TS / 102400.f;
        float tvar = fmaxf(TQ/102400.f - tm*tm, 0.f);
        fin[0] = vm; fin[1] = rsqrtf(vvar + EPS);
        fin[2] = tm; fin[3] = rsqrtf(tvar + EPS);
    }
}

// K3: sum2_raw[n,d,l] = sum_ch Ws[d,ch]*F(n, ch*325+l); per-d stat partials.
__global__ __launch_bounds__(256) void k3_conv(
    const float* __restrict__ time_pre, const float* __restrict__ view_pre,
    const float* __restrict__ fin, const float* __restrict__ Ws,
    const float* __restrict__ g_t, const float* __restrict__ be_t,
    const float* __restrict__ g_v, const float* __restrict__ be_v,
    float* __restrict__ sum2_raw, float* __restrict__ chan_part)
{
    const int n = blockIdx.y, lc = blockIdx.x;
    const int tid = threadIdx.x, lane = tid & 63, vg = tid >> 6;
    const int l = lc*64 + lane;
    __shared__ float Ft[64][64];    // [ch][lane]
    __shared__ float Wsh[64][64];   // [d][ch]
    for (int i = tid; i < 4096; i += 256) Wsh[i>>6][i&63] = Ws[i];
    const float vm = fin[0], vi = fin[1], tm = fin[2], ti = fin[3];
    const float gt = g_t[0]*ti, bt = be_t[0] - tm*g_t[0]*ti;
    const float gv = g_v[0]*vi, bv = be_v[0] - vm*g_v[0]*vi;
    const bool lval = (l < 325);
    #pragma unroll
    for (int k=0;k<16;k++){
        int ch = vg + 4*k;
        float val = 0.f;
        if (lval){
            int idx = ch*325 + l;
            if (idx < 1600) val = hsw(time_pre[n*1600 + idx]*gt + bt);
            else            val = hsw(view_pre[n*19200 + idx - 1600]*gv + bv);
        }
        Ft[ch][lane] = val;
    }
    __syncthreads();
    float acc[16];
    #pragma unroll
    for (int k=0;k<16;k++) acc[k]=0.f;
    #pragma unroll
    for (int cc=0;cc<64;cc+=8){
        float f8[8];
        #pragma unroll
        for (int i=0;i<8;i++) f8[i] = Ft[cc+i][lane];
        #pragma unroll
        for (int k=0;k<16;k++){
            int d = vg + 4*k;
            #pragma unroll
            for (int i=0;i<8;i++) acc[k] += f8[i]*Wsh[d][cc+i];
        }
    }
    #pragma unroll
    for (int k=0;k<16;k++){
        int d = vg + 4*k;
        float a = lval ? acc[k] : 0.f;
        if (lval) sum2_raw[n*20800 + d*325 + l] = a;
        float s = a, q = a*a;
        #pragma unroll
        for (int o=32;o>0;o>>=1){ s += __shfl_down(s,o); q += __shfl_down(q,o); }
        if (lane == 0){
            int b = n*6 + lc;
            chan_part[b*128 + d*2]   = s;
            chan_part[b*128 + d*2+1] = q;
        }
    }
}

// K4: per-channel BN stats.
__global__ void k4_chanstats(const float* __restrict__ chan_part, float* __restrict__ chan_stats)
{
    int d = threadIdx.x;
    float S=0.f, Q=0.f;
    for (int b=0;b<384;b++){ S += chan_part[b*128 + d*2]; Q += chan_part[b*128 + d*2+1]; }
    float m = S/20800.f;
    float var = fmaxf(Q/20800.f - m*m, 0.f);
    chan_stats[d*2] = m;
    chan_stats[d*2+1] = rsqrtf(var + EPS);
}

// K5: xbar[d,l] = mean_n hswish(bn(sum2_raw)).
__global__ __launch_bounds__(256) void k5_xbar(
    const float* __restrict__ sum2_raw, const float* __restrict__ chan_stats,
    const float* __restrict__ g_s, const float* __restrict__ be_s,
    float* __restrict__ xbar)
{
    int g = blockIdx.x*256 + threadIdx.x;
    if (g >= 20800) return;
    int d = g / 325;
    float m = chan_stats[d*2], istd = chan_stats[d*2+1];
    float ga = g_s[d]*istd, bb = be_s[d] - m*ga;
    float acc = 0.f;
    for (int n=0;n<64;n++) acc += hsw(sum2_raw[n*20800 + g]*ga + bb);
    xbar[g] = acc * (1.f/64.f);
}

// K6: gates. l<300 -> x_time output (sigmoid); l>=300 -> scale[v][c]=tanh(sigmoid)+1.
__global__ __launch_bounds__(64) void k6_gates(
    const float* __restrict__ xbar, const float* __restrict__ W2t,
    const float* __restrict__ b2t, const float* __restrict__ W2v,
    const float* __restrict__ b2v, float* __restrict__ out_time,
    float* __restrict__ scale_vc)
{
    int l = blockIdx.x, tid = threadIdx.x;
    __shared__ float xb[64];
    xb[tid] = xbar[tid*325 + l];
    __syncthreads();
    if (l < 300){
        float acc = b2t[tid];
        for (int d=0; d<64; d++) acc += W2t[tid*64+d]*xb[d];
        out_time[tid*300 + l] = sigm(acc);
    } else {
        int v = l - 300;
        float acc = b2v[tid];
        for (int d=0; d<64; d++) acc += W2v[tid*64+d]*xb[d];
        scale_vc[v*64 + tid] = tanhf(sigm(acc)) + 1.f;
    }
}

// K7: y[n*300+t][v*64+d] = sum_c x[n,c,t,v]*scale[v,c]*Lw[c,d]  (bf16 store)
__global__ __launch_bounds__(256) void k7_einsum(
    const float* __restrict__ x0, const int* __restrict__ shift_in,
    const float* __restrict__ scale_vc, const float* __restrict__ Lw,
    __hip_bfloat16* __restrict__ y)
{
    const int n = blockIdx.y, tc = blockIdx.x, t0 = tc*10;
    const int tid = threadIdx.x, d = tid & 63, vg = tid >> 6;
    const float* xn = x0 + n*480000;
    __shared__ float xs[25][64];   // [v][c]
    float lwreg[64];
    #pragma unroll
    for (int c=0;c<64;c++) lwreg[c] = Lw[c*64 + d];
    int off[7]; float scl[7];
    #pragma unroll
    for (int k=0;k<7;k++){
        int v = vg + 4*k;
        if (v < 25){
            int s = shift_in[v*64 + d];       // 'd' doubles as staging c-index
            off[k] = (s & 63)*7500 + (s >> 6);
            scl[k] = scale_vc[v*64 + d];
        } else { off[k]=0; scl[k]=0.f; }
    }
    for (int tt=0; tt<10; tt++){
        int t = t0 + tt;
        #pragma unroll
        for (int k=0;k<7;k++){
            int v = vg + 4*k;
            if (v < 25) xs[v][d] = xn[off[k] + t*25] * scl[k];
        }
        __syncthreads();
        float acc[7];
        #pragma unroll
        for (int k=0;k<7;k++) acc[k] = 0.f;
        #pragma unroll
        for (int cc=0; cc<64; cc+=8){
            #pragma unroll
            for (int k=0;k<7;k++){
                int v = vg + 4*k;
                if (v < 25){
                    float4 a = *reinterpret_cast<const float4*>(&xs[v][cc]);
                    float4 b = *reinterpret_cast<const float4*>(&xs[v][cc+4]);
                    acc[k] += a.x*lwreg[cc]   + a.y*lwreg[cc+1] + a.z*lwreg[cc+2] + a.w*lwreg[cc+3]
                            + b.x*lwreg[cc+4] + b.y*lwreg[cc+5] + b.z*lwreg[cc+6] + b.w*lwreg[cc+7];
                }
            }
        }
        __hip_bfloat16* yr = y + (n*300 + t)*1600;
        #pragma unroll
        for (int k=0;k<7;k++){
            int v = vg + 4*k;
            if (v < 25) yr[v*64 + d] = __float2bfloat16(acc[k]);
        }
        __syncthreads();
    }
}

// K8: per-column (sum, sumsq) partials of y over 120-row stripes.
__global__ __launch_bounds__(256) void k8_colpart(
    const __hip_bfloat16* __restrict__ y, float* __restrict__ col_part)
{
    const int b = blockIdx.x, tid = threadIdx.x;
    const int r0 = b*120;
    float s[7], q[7];
    #pragma unroll
    for (int k=0;k<7;k++){ s[k]=0.f; q[k]=0.f; }
    for (int r=r0; r<r0+120; r++){
        const __hip_bfloat16* yr = y + r*1600;
        #pragma unroll
        for (int k=0;k<7;k++){
            int col = tid + 256*k;
            if (col < 1600){
                float v = __bfloat162float(yr[col]);
                s[k] += v; q[k] += v*v;
            }
        }
    }
    #pragma unroll
    for (int k=0;k<7;k++){
        int col = tid + 256*k;
        if (col < 1600){
            col_part[b*3200 + col*2]   = s[k];
            col_part[b*3200 + col*2+1] = q[k];
        }
    }
}

// K8b: final per-column stats.
__global__ __launch_bounds__(256) void k8b_colstats(
    const float* __restrict__ col_part, float* __restrict__ col_stats)
{
    int col = blockIdx.x*256 + threadIdx.x;
    if (col >= 1600) return;
    float S=0.f, Q=0.f;
    for (int b=0;b<160;b++){ S += col_part[b*3200 + col*2]; Q += col_part[b*3200 + col*2+1]; }
    float m = S/19200.f;
    float var = fmaxf(Q/19200.f - m*m, 0.f);
    col_stats[col*2] = m;
    col_stats[col*2+1] = rsqrtf(var + EPS);
}

// K9: out[n,d,t,v] = relu( bn(y[n*300+t, shift_out[v*64+d]]) + x0[n,d,t,v] )
__global__ __launch_bounds__(256) void k9_final(
    const float* __restrict__ x0, const __hip_bfloat16* __restrict__ y,
    const int* __restrict__ shift_out, const float* __restrict__ col_stats,
    const float* __restrict__ g_bn, const float* __restrict__ be_bn,
    float* __restrict__ out)
{
    int b = blockIdx.x;
    int q = gridDim.x >> 3;                   // gridDim.x % 8 == 0
    int bs = (b & 7)*q + (b >> 3);            // XCD-contiguous swizzle
    int idx = bs*256 + (int)threadIdx.x;      // < 30,720,000
    int v = idx % 25;
    int t = (idx / 25) % 300;
    int d = (idx / 7500) % 64;
    int n = idx / 480000;
    int j = v*64 + d;
    int s = shift_out[j];
    float yv = __bfloat162float(y[(n*300 + t)*1600 + s]);
    float m = col_stats[s*2], istd = col_stats[s*2+1];
    float val = (yv - m)*istd*g_bn[j] + be_bn[j] + x0[idx];
    out[idx] = fmaxf(val, 0.f);
}

extern "C" void kernel_launch(void* const* d_in, const int* in_sizes, int n_in,
                              void* d_out, int out_size, void* d_ws, size_t ws_size,
                              hipStream_t stream)
{
    const float* x0       = (const float*)d_in[0];
    const int*   shift_in = (const int*)d_in[1];
    const int*   shift_out= (const int*)d_in[2];
    const float* Wv       = (const float*)d_in[3];
    const float* g_v      = (const float*)d_in[5];
    const float* be_v     = (const float*)d_in[6];
    const float* Wt       = (const float*)d_in[7];
    const float* g_t      = (const float*)d_in[9];
    const float* be_t     = (const float*)d_in[10];
    const float* Ws       = (const float*)d_in[11];
    const float* g_s      = (const float*)d_in[13];
    const float* be_s     = (const float*)d_in[14];
    const float* W2t      = (const float*)d_in[15];
    const float* b2t      = (const float*)d_in[16];
    const float* W2v      = (const float*)d_in[17];
    const float* b2v      = (const float*)d_in[18];
    const float* Lw       = (const float*)d_in[19];
    const float* g_bn     = (const float*)d_in[21];
    const float* be_bn    = (const float*)d_in[22];
    // biases bv(4), bt(8), bs(12), Lb(20) cancel inside the following BNs.

    float* ws = (float*)d_ws;
    float* view_pre  = ws;                  // 1,228,800
    float* time_part = ws + 1228800;        // 3,072,000
    float* time_pre  = ws + 4300800;        //   102,400
    float* view_part = ws + 4403200;        //     3,840
    float* tstat_part= ws + 4407040;        //       800
    float* fin       = ws + 4407840;        //         8
    float* sum2_raw  = ws + 4407848;        // 1,331,200
    float* chan_part = ws + 5739048;        //    49,152
    float* chan_stats= ws + 5788200;        //       128
    float* xbar      = ws + 5788328;        //    20,800
    float* scale_vc  = ws + 5809128;        //     1,600
    float* col_part  = ws + 5810728;        //   512,000
    float* col_stats = ws + 6322728;        //     3,200
    __hip_bfloat16* y = (__hip_bfloat16*)(ws + 6325928); // 30,720,000 bf16

    float* out      = (float*)d_out;
    float* out_time = out + 30720000;

    k1_viewtime   <<<dim3(30,64), 256, 0, stream>>>(x0, shift_in, Wv, Wt, view_pre, time_part, view_part);
    k2a_timereduce<<<400, 256, 0, stream>>>(time_part, time_pre, tstat_part);
    k2b_finstats  <<<1, 256, 0, stream>>>(view_part, tstat_part, fin);
    k3_conv       <<<dim3(6,64), 256, 0, stream>>>(time_pre, view_pre, fin, Ws, g_t, be_t, g_v, be_v, sum2_raw, chan_part);
    k4_chanstats  <<<1, 64, 0, stream>>>(chan_part, chan_stats);
    k5_xbar       <<<82, 256, 0, stream>>>(sum2_raw, chan_stats, g_s, be_s, xbar);
    k6_gates      <<<325, 64, 0, stream>>>(xbar, W2t, b2t, W2v, b2v, out_time, scale_vc);
    k7_einsum     <<<dim3(30,64), 256, 0, stream>>>(x0, shift_in, scale_vc, Lw, y);
    k8_colpart    <<<160, 256, 0, stream>>>(y, col_part);
    k8b_colstats  <<<7, 256, 0, stream>>>(col_part, col_stats);
    k9_final      <<<120000, 256, 0, stream>>>(x0, y, shift_out, col_stats, g_bn, be_bn, out);
}

// Round 2
// 515.378 us; speedup vs baseline: 1.9493x; 1.9493x over previous
//
#include <hip/hip_runtime.h>
#include <hip/hip_bf16.h>

#define EPS 1e-5f

typedef __bf16 bf16x8 __attribute__((ext_vector_type(8)));
typedef float f32x4 __attribute__((ext_vector_type(4)));

__device__ __forceinline__ float hsw(float x){
    float t = fminf(fmaxf(x + 3.f, 0.f), 6.f);
    return x * t * (1.f/6.f);
}
__device__ __forceinline__ float sigm(float x){ return 1.f/(1.f + expf(-x)); }

// K1: stage x0[n,:,t0..t0+11,:] in LDS (coalesced), gather via shift_in from LDS,
// write x_perm[n,t,v,c] (bf16, coalesced), accumulate view/time conv partials.
__global__ __launch_bounds__(256) void k1_viewtime(
    const float* __restrict__ x0, const int* __restrict__ shift_in,
    const float* __restrict__ Wv, const float* __restrict__ Wt,
    float* __restrict__ view_pre, float* __restrict__ time_part,
    float* __restrict__ view_part, __hip_bfloat16* __restrict__ x_perm)
{
    const int tc = blockIdx.x, n = blockIdx.y, t0 = tc*12;
    const int tid = threadIdx.x;
    __shared__ __hip_bfloat16 lx[64*300];   // [c'][tt*25+v']
    __shared__ float red[4][64][12];
    __shared__ float rs[8];
    const float* xb = x0 + n*480000 + t0*25;
    for (int i = tid; i < 4800; i += 256){
        int row = i/75, c4 = i - row*75;
        float4 f = *reinterpret_cast<const float4*>(xb + row*7500 + c4*4);
        union { uint2 u; __hip_bfloat16 h[4]; } pk;
        pk.h[0]=__float2bfloat16(f.x); pk.h[1]=__float2bfloat16(f.y);
        pk.h[2]=__float2bfloat16(f.z); pk.h[3]=__float2bfloat16(f.w);
        *reinterpret_cast<uint2*>(&lx[row*300 + c4*4]) = pk.u;
    }
    float wt[12];
    #pragma unroll
    for (int tt=0;tt<12;tt++) wt[tt] = Wt[t0+tt];
    __syncthreads();
    const int c = tid & 63, vg = tid >> 6;
    float vacc[12];
    #pragma unroll
    for (int tt=0;tt<12;tt++) vacc[tt]=0.f;
    for (int k=0;k<7;k++){
        int v = vg + 4*k;
        if (v < 25){
            int s = shift_in[v*64+c];
            int base = (s&63)*300 + (s>>6);
            float wv = Wv[v];
            float tacc = 0.f;
            __hip_bfloat16* xo = x_perm + ((n*300+t0)*25 + v)*64 + c;
            #pragma unroll
            for (int tt=0;tt<12;tt++){
                __hip_bfloat16 hb = lx[base + tt*25];
                float val = __bfloat162float(hb);
                tacc += wt[tt]*val;
                vacc[tt] += wv*val;
                xo[tt*1600] = hb;
            }
            time_part[(n*25+tc)*1600 + c*25 + v] = tacc;
        }
    }
    #pragma unroll
    for (int tt=0;tt<12;tt++) red[vg][c][tt] = vacc[tt];
    __syncthreads();
    float vs=0.f, vq=0.f;
    for (int i = tid; i < 768; i += 256){
        int tt = i>>6, c2 = i&63;
        float tot = red[0][c2][tt]+red[1][c2][tt]+red[2][c2][tt]+red[3][c2][tt];
        view_pre[n*19200 + c2*300 + t0+tt] = tot;
        vs += tot; vq += tot*tot;
    }
    #pragma unroll
    for (int o=32;o>0;o>>=1){ vs += __shfl_down(vs,o); vq += __shfl_down(vq,o); }
    if ((tid&63)==0){ rs[(tid>>6)*2]=vs; rs[(tid>>6)*2+1]=vq; }
    __syncthreads();
    if (tid==0){
        view_part[(n*25+tc)*2]   = rs[0]+rs[2]+rs[4]+rs[6];
        view_part[(n*25+tc)*2+1] = rs[1]+rs[3]+rs[5]+rs[7];
    }
}

// K2a: reduce time partials over 25 chunks -> time_pre; block stat partials.
__global__ __launch_bounds__(256) void k2a_timereduce(
    const float* __restrict__ time_part, float* __restrict__ time_pre,
    float* __restrict__ tstat_part)
{
    int g = blockIdx.x*256 + threadIdx.x;   // [0, 102400)
    int n = g / 1600, r = g % 1600;
    float s = 0.f;
    for (int tc=0; tc<25; tc++) s += time_part[(n*25+tc)*1600 + r];
    time_pre[g] = s;
    float a = s, b = s*s;
    __shared__ float ls[8];
    #pragma unroll
    for (int o=32;o>0;o>>=1){ a += __shfl_down(a,o); b += __shfl_down(b,o); }
    int wid = threadIdx.x >> 6;
    if ((threadIdx.x & 63) == 0){ ls[wid*2] = a; ls[wid*2+1] = b; }
    __syncthreads();
    if (threadIdx.x == 0){
        tstat_part[blockIdx.x*2]   = ls[0]+ls[2]+ls[4]+ls[6];
        tstat_part[blockIdx.x*2+1] = ls[1]+ls[3]+ls[5]+ls[7];
    }
}

// K2b: final scalar BN stats for view/time branches.
__global__ __launch_bounds__(256) void k2b_finstats(
    const float* __restrict__ view_part, const float* __restrict__ tstat_part,
    float* __restrict__ fin)
{
    float acc[4] = {0.f,0.f,0.f,0.f};
    for (int i=threadIdx.x; i<1600; i+=256){ acc[0] += view_part[2*i]; acc[1] += view_part[2*i+1]; }
    for (int i=threadIdx.x; i<400;  i+=256){ acc[2] += tstat_part[2*i]; acc[3] += tstat_part[2*i+1]; }
    __shared__ float ls[4][4];
    int wid = threadIdx.x>>6, lane = threadIdx.x&63;
    #pragma unroll
    for (int j=0;j<4;j++){
        float a = acc[j];
        #pragma unroll
        for (int o=32;o>0;o>>=1) a += __shfl_down(a,o);
        if (lane==0) ls[j][wid] = a;
    }
    __syncthreads();
    if (threadIdx.x==0){
        float VS=ls[0][0]+ls[0][1]+ls[0][2]+ls[0][3];
        float VQ=ls[1][0]+ls[1][1]+ls[1][2]+ls[1][3];
        float TS=ls[2][0]+ls[2][1]+ls[2][2]+ls[2][3];
        float TQ=ls[3][0]+ls[3][1]+ls[3][2]+ls[3][3];
        float vm = VS / 1228800.f;
        float vvar = fmaxf(VQ/1228800.f - vm*vm, 0.f);
        float tm = TS / 102400.f;
        float tvar = fmaxf(TQ/102400.f - tm*tm, 0.f);
        fin[0] = vm; fin[1] = rsqrtf(vvar + EPS);
        fin[2] = tm; fin[3] = rsqrtf(tvar + EPS);
    }
}

// K3: sum2_raw[n,d,l] = sum_ch Ws[d,ch]*F(n, ch*325+l); per-d stat partials.
__global__ __launch_bounds__(256) void k3_conv(
    const float* __restrict__ time_pre, const float* __restrict__ view_pre,
    const float* __restrict__ fin, const float* __restrict__ Ws,
    const float* __restrict__ g_t, const float* __restrict__ be_t,
    const float* __restrict__ g_v, const float* __restrict__ be_v,
    float* __restrict__ sum2_raw, float* __restrict__ chan_part)
{
    const int n = blockIdx.y, lc = blockIdx.x;
    const int tid = threadIdx.x, lane = tid & 63, vg = tid >> 6;
    const int l = lc*64 + lane;
    __shared__ float Ft[64][64];    // [ch][lane]
    __shared__ float Wsh[64][64];   // [d][ch]
    for (int i = tid; i < 4096; i += 256) Wsh[i>>6][i&63] = Ws[i];
    const float vm = fin[0], vi = fin[1], tm = fin[2], ti = fin[3];
    const float gt = g_t[0]*ti, bt = be_t[0] - tm*g_t[0]*ti;
    const float gv = g_v[0]*vi, bv = be_v[0] - vm*g_v[0]*vi;
    const bool lval = (l < 325);
    #pragma unroll
    for (int k=0;k<16;k++){
        int ch = vg + 4*k;
        float val = 0.f;
        if (lval){
            int idx = ch*325 + l;
            if (idx < 1600) val = hsw(time_pre[n*1600 + idx]*gt + bt);
            else            val = hsw(view_pre[n*19200 + idx - 1600]*gv + bv);
        }
        Ft[ch][lane] = val;
    }
    __syncthreads();
    float acc[16];
    #pragma unroll
    for (int k=0;k<16;k++) acc[k]=0.f;
    #pragma unroll
    for (int cc=0;cc<64;cc+=8){
        float f8[8];
        #pragma unroll
        for (int i=0;i<8;i++) f8[i] = Ft[cc+i][lane];
        #pragma unroll
        for (int k=0;k<16;k++){
            int d = vg + 4*k;
            #pragma unroll
            for (int i=0;i<8;i++) acc[k] += f8[i]*Wsh[d][cc+i];
        }
    }
    #pragma unroll
    for (int k=0;k<16;k++){
        int d = vg + 4*k;
        float a = lval ? acc[k] : 0.f;
        if (lval) sum2_raw[n*20800 + d*325 + l] = a;
        float s = a, q = a*a;
        #pragma unroll
        for (int o=32;o>0;o>>=1){ s += __shfl_down(s,o); q += __shfl_down(q,o); }
        if (lane == 0){
            int b = n*6 + lc;
            chan_part[b*128 + d*2]   = s;
            chan_part[b*128 + d*2+1] = q;
        }
    }
}

// K4: per-channel BN stats.
__global__ void k4_chanstats(const float* __restrict__ chan_part, float* __restrict__ chan_stats)
{
    int d = threadIdx.x;
    float S=0.f, Q=0.f;
    for (int b=0;b<384;b++){ S += chan_part[b*128 + d*2]; Q += chan_part[b*128 + d*2+1]; }
    float m = S/20800.f;
    float var = fmaxf(Q/20800.f - m*m, 0.f);
    chan_stats[d*2] = m;
    chan_stats[d*2+1] = rsqrtf(var + EPS);
}

// K5: xbar[d,l] = mean_n hswish(bn(sum2_raw)).
__global__ __launch_bounds__(256) void k5_xbar(
    const float* __restrict__ sum2_raw, const float* __restrict__ chan_stats,
    const float* __restrict__ g_s, const float* __restrict__ be_s,
    float* __restrict__ xbar)
{
    int g = blockIdx.x*256 + threadIdx.x;
    if (g >= 20800) return;
    int d = g / 325;
    float m = chan_stats[d*2], istd = chan_stats[d*2+1];
    float ga = g_s[d]*istd, bb = be_s[d] - m*ga;
    float acc = 0.f;
    for (int n=0;n<64;n++) acc += hsw(sum2_raw[n*20800 + g]*ga + bb);
    xbar[g] = acc * (1.f/64.f);
}

// K6: gates. l<300 -> x_time output (sigmoid); l>=300 -> scale[v][c]=tanh(sigmoid)+1.
__global__ __launch_bounds__(64) void k6_gates(
    const float* __restrict__ xbar, const float* __restrict__ W2t,
    const float* __restrict__ b2t, const float* __restrict__ W2v,
    const float* __restrict__ b2v, float* __restrict__ out_time,
    float* __restrict__ scale_vc)
{
    int l = blockIdx.x, tid = threadIdx.x;
    __shared__ float xb[64];
    xb[tid] = xbar[tid*325 + l];
    __syncthreads();
    if (l < 300){
        float acc = b2t[tid];
        for (int d=0; d<64; d++) acc += W2t[tid*64+d]*xb[d];
        out_time[tid*300 + l] = sigm(acc);
    } else {
        int v = l - 300;
        float acc = b2v[tid];
        for (int d=0; d<64; d++) acc += W2v[tid*64+d]*xb[d];
        scale_vc[v*64 + tid] = tanhf(sigm(acc)) + 1.f;
    }
}

// K7: y[r][d] = sum_c x_perm[r][c]*scale[r%25][c]*Lw[c][d], MFMA bf16.
// y aliases x_perm (in-place, row-disjoint across blocks; reads staged before writes).
__global__ __launch_bounds__(256) void k7_mfma(
    const __hip_bfloat16* __restrict__ x_perm, const float* __restrict__ scale_vc,
    const float* __restrict__ Lw, __hip_bfloat16* __restrict__ y)
{
    __shared__ __hip_bfloat16 As[256*64];
    __shared__ __hip_bfloat16 Bs[64*64];
    const int tid = threadIdx.x;
    const int row0 = blockIdx.x*256;
    // stage B^T (Bs[d][c] = Lw[c][d]) with XOR swizzle on 8-elem chunks
    for (int i = tid; i < 4096; i += 256){
        int d = i>>6, cc = i&63;
        int sw = (((cc>>3) ^ (d&7))<<3) + (cc&7);
        Bs[d*64 + sw] = __float2bfloat16(Lw[cc*64 + d]);
    }
    // stage A (scaled) with XOR swizzle
    for (int i = tid; i < 2048; i += 256){
        int row = i>>3, cc = i&7;
        int grow = row0 + row;
        int v = grow % 25;
        union { float4 f; unsigned short u[8]; } raw;
        raw.f = *reinterpret_cast<const float4*>(x_perm + grow*64 + cc*8);
        const float* sc = scale_vc + v*64 + cc*8;
        __hip_bfloat16 tmp[8];
        #pragma unroll
        for (int j=0;j<8;j++){
            float f = __uint_as_float((unsigned)raw.u[j] << 16);
            tmp[j] = __float2bfloat16(f * sc[j]);
        }
        int swc = (cc ^ (row&7))<<3;
        *reinterpret_cast<float4*>(&As[row*64 + swc]) = *reinterpret_cast<const float4*>(tmp);
    }
    __syncthreads();
    const int wave = tid>>6, lane = tid&63;
    const int lrow = lane&15, lk = lane>>4;
    f32x4 acc[4][4];
    #pragma unroll
    for (int mt=0;mt<4;mt++)
      #pragma unroll
      for (int nt=0;nt<4;nt++) acc[mt][nt] = (f32x4){0.f,0.f,0.f,0.f};
    #pragma unroll
    for (int ks=0;ks<2;ks++){
        bf16x8 a[4], b[4];
        int kc = ks*4 + lk;
        #pragma unroll
        for (int mt=0;mt<4;mt++){
            int row = wave*64 + mt*16 + lrow;
            a[mt] = *reinterpret_cast<const bf16x8*>(&As[row*64 + ((kc ^ (row&7))<<3)]);
        }
        #pragma unroll
        for (int nt=0;nt<4;nt++){
            int d = nt*16 + lrow;
            b[nt] = *reinterpret_cast<const bf16x8*>(&Bs[d*64 + ((kc ^ (d&7))<<3)]);
        }
        #pragma unroll
        for (int mt=0;mt<4;mt++)
          #pragma unroll
          for (int nt=0;nt<4;nt++)
            acc[mt][nt] = __builtin_amdgcn_mfma_f32_16x16x32_bf16(a[mt], b[nt], acc[mt][nt], 0, 0, 0);
    }
    #pragma unroll
    for (int mt=0;mt<4;mt++){
        int growb = row0 + wave*64 + mt*16 + lk*4;
        #pragma unroll
        for (int nt=0;nt<4;nt++){
            int col = nt*16 + lrow;
            #pragma unroll
            for (int j=0;j<4;j++)
                y[(growb + j)*64 + col] = __float2bfloat16(acc[mt][nt][j]);
        }
    }
}

// K8: per-column (sum, sumsq) partials of y over 120-row stripes.
__global__ __launch_bounds__(256) void k8_colpart(
    const __hip_bfloat16* __restrict__ y, float* __restrict__ col_part)
{
    const int b = blockIdx.x, tid = threadIdx.x;
    const int r0 = b*120;
    float s[7], q[7];
    #pragma unroll
    for (int k=0;k<7;k++){ s[k]=0.f; q[k]=0.f; }
    for (int r=r0; r<r0+120; r++){
        const __hip_bfloat16* yr = y + r*1600;
        #pragma unroll
        for (int k=0;k<7;k++){
            int col = tid + 256*k;
            if (col < 1600){
                float v = __bfloat162float(yr[col]);
                s[k] += v; q[k] += v*v;
            }
        }
    }
    #pragma unroll
    for (int k=0;k<7;k++){
        int col = tid + 256*k;
        if (col < 1600){
            col_part[b*3200 + col*2]   = s[k];
            col_part[b*3200 + col*2+1] = q[k];
        }
    }
}

// K8b: final per-column stats.
__global__ __launch_bounds__(256) void k8b_colstats(
    const float* __restrict__ col_part, float* __restrict__ col_stats)
{
    int col = blockIdx.x*256 + threadIdx.x;
    if (col >= 1600) return;
    float S=0.f, Q=0.f;
    for (int b=0;b<160;b++){ S += col_part[b*3200 + col*2]; Q += col_part[b*3200 + col*2+1]; }
    float m = S/19200.f;
    float var = fmaxf(Q/19200.f - m*m, 0.f);
    col_stats[col*2] = m;
    col_stats[col*2+1] = rsqrtf(var + EPS);
}

// K8c: fused per-j BN params: jP[j] = (A, B, bits(shift_out[j]), 0)
__global__ __launch_bounds__(256) void k8c_jparams(
    const int* __restrict__ shift_out, const float* __restrict__ col_stats,
    const float* __restrict__ g_bn, const float* __restrict__ be_bn,
    float4* __restrict__ jP)
{
    int j = blockIdx.x*256 + threadIdx.x;
    if (j >= 1600) return;
    int s = shift_out[j];
    float m = col_stats[s*2], istd = col_stats[s*2+1];
    float A = istd * g_bn[j];
    float B = be_bn[j] - m*A;
    jP[j] = make_float4(A, B, __int_as_float(s), 0.f);
}

// K9: stage 12 contiguous y rows in LDS, gather from LDS, coalesced x0/out.
__global__ __launch_bounds__(256) void k9_final(
    const float* __restrict__ x0, const __hip_bfloat16* __restrict__ y,
    const float4* __restrict__ jP, float* __restrict__ out)
{
    const int tc = blockIdx.x, n = blockIdx.y, t0 = tc*12;
    const int tid = threadIdx.x;
    __shared__ __hip_bfloat16 ys[19200];
    const __hip_bfloat16* yb = y + (n*300 + t0)*1600;
    for (int i = tid; i < 2400; i += 256)
        *reinterpret_cast<float4*>(&ys[i*8]) = *reinterpret_cast<const float4*>(yb + i*8);
    __syncthreads();
    const int base_x = n*480000 + t0*25;
    for (int k=0;k<75;k++){
        int e = k*256 + tid;
        int d = e/300;
        int rem = e - d*300;
        int tt = rem/25;
        int v = rem - tt*25;
        float4 p = jP[v*64 + d];
        int s = __float_as_int(p.z);
        float yv = __bfloat162float(ys[tt*1600 + s]);
        int idx = base_x + d*7500 + rem;
        out[idx] = fmaxf(fmaf(yv, p.x, p.y) + x0[idx], 0.f);
    }
}

extern "C" void kernel_launch(void* const* d_in, const int* in_sizes, int n_in,
                              void* d_out, int out_size, void* d_ws, size_t ws_size,
                              hipStream_t stream)
{
    const float* x0       = (const float*)d_in[0];
    const int*   shift_in = (const int*)d_in[1];
    const int*   shift_out= (const int*)d_in[2];
    const float* Wv       = (const float*)d_in[3];
    const float* g_v      = (const float*)d_in[5];
    const float* be_v     = (const float*)d_in[6];
    const float* Wt       = (const float*)d_in[7];
    const float* g_t      = (const float*)d_in[9];
    const float* be_t     = (const float*)d_in[10];
    const float* Ws       = (const float*)d_in[11];
    const float* g_s      = (const float*)d_in[13];
    const float* be_s     = (const float*)d_in[14];
    const float* W2t      = (const float*)d_in[15];
    const float* b2t      = (const float*)d_in[16];
    const float* W2v      = (const float*)d_in[17];
    const float* b2v      = (const float*)d_in[18];
    const float* Lw       = (const float*)d_in[19];
    const float* g_bn     = (const float*)d_in[21];
    const float* be_bn    = (const float*)d_in[22];
    // biases bv(4), bt(8), bs(12), Lb(20) cancel inside the following BNs.

    float* ws = (float*)d_ws;
    float* view_pre  = ws;                  // 1,228,800
    float* time_part = ws + 1228800;        // 2,560,000
    float* time_pre  = ws + 3788800;        //   102,400
    float* view_part = ws + 3891200;        //     3,200
    float* tstat_part= ws + 3894400;        //       800
    float* fin       = ws + 3895200;        //         8
    float* sum2_raw  = ws + 3895208;        // 1,331,200
    float* chan_part = ws + 5226408;        //    49,152
    float* chan_stats= ws + 5275560;        //       128
    float* xbar      = ws + 5275688;        //    20,800
    float* scale_vc  = ws + 5296488;        //     1,600
    float* col_part  = ws + 5298088;        //   512,000
    float* col_stats = ws + 5810088;        //     3,200
    float4* jP       = (float4*)(ws + 5813288); // 1,600 float4 (16B-aligned)
    __hip_bfloat16* x_perm = (__hip_bfloat16*)(ws + 5819688); // 30,720,000 bf16
    __hip_bfloat16* y = x_perm;             // in-place alias (row-wise 1:1)

    float* out      = (float*)d_out;
    float* out_time = out + 30720000;

    k1_viewtime   <<<dim3(25,64), 256, 0, stream>>>(x0, shift_in, Wv, Wt, view_pre, time_part, view_part, x_perm);
    k2a_timereduce<<<400, 256, 0, stream>>>(time_part, time_pre, tstat_part);
    k2b_finstats  <<<1, 256, 0, stream>>>(view_part, tstat_part, fin);
    k3_conv       <<<dim3(6,64), 256, 0, stream>>>(time_pre, view_pre, fin, Ws, g_t, be_t, g_v, be_v, sum2_raw, chan_part);
    k4_chanstats  <<<1, 64, 0, stream>>>(chan_part, chan_stats);
    k5_xbar       <<<82, 256, 0, stream>>>(sum2_raw, chan_stats, g_s, be_s, xbar);
    k6_gates      <<<325, 64, 0, stream>>>(xbar, W2t, b2t, W2v, b2v, out_time, scale_vc);
    k7_mfma       <<<1875, 256, 0, stream>>>(x_perm, scale_vc, Lw, y);
    k8_colpart    <<<160, 256, 0, stream>>>(y, col_part);
    k8b_colstats  <<<7, 256, 0, stream>>>(col_part, col_stats);
    k8c_jparams   <<<7, 256, 0, stream>>>(shift_out, col_stats, g_bn, be_bn, jP);
    k9_final      <<<dim3(25,64), 256, 0, stream>>>(x0, y, jP, out);
}

// Round 3
// 369.370 us; speedup vs baseline: 2.7199x; 1.3953x over previous
//
#include <hip/hip_runtime.h>
#include <hip/hip_bf16.h>

#define EPS 1e-5f

typedef __bf16 bf16x8 __attribute__((ext_vector_type(8)));
typedef float f32x4 __attribute__((ext_vector_type(4)));

__device__ __forceinline__ float hsw(float x){
    float t = fminf(fmaxf(x + 3.f, 0.f), 6.f);
    return x * t * (1.f/6.f);
}
__device__ __forceinline__ float sigm(float x){ return 1.f/(1.f + expf(-x)); }

// K1: stage x0[n,:,t0..t0+11,:] in LDS (coalesced), gather via shift_in from LDS,
// write x_perm[n,t,v,c] (bf16, coalesced), accumulate view/time conv partials.
__global__ __launch_bounds__(256) void k1_viewtime(
    const float* __restrict__ x0, const int* __restrict__ shift_in,
    const float* __restrict__ Wv, const float* __restrict__ Wt,
    float* __restrict__ view_pre, float* __restrict__ time_part,
    float* __restrict__ view_part, __hip_bfloat16* __restrict__ x_perm)
{
    const int tc = blockIdx.x, n = blockIdx.y, t0 = tc*12;
    const int tid = threadIdx.x;
    __shared__ __hip_bfloat16 lx[64*300];   // [c'][tt*25+v']
    __shared__ float red[4][64][12];
    __shared__ float rs[8];
    const float* xb = x0 + n*480000 + t0*25;
    for (int i = tid; i < 4800; i += 256){
        int row = i/75, c4 = i - row*75;
        float4 f = *reinterpret_cast<const float4*>(xb + row*7500 + c4*4);
        union { uint2 u; __hip_bfloat16 h[4]; } pk;
        pk.h[0]=__float2bfloat16(f.x); pk.h[1]=__float2bfloat16(f.y);
        pk.h[2]=__float2bfloat16(f.z); pk.h[3]=__float2bfloat16(f.w);
        *reinterpret_cast<uint2*>(&lx[row*300 + c4*4]) = pk.u;
    }
    float wt[12];
    #pragma unroll
    for (int tt=0;tt<12;tt++) wt[tt] = Wt[t0+tt];
    __syncthreads();
    const int c = tid & 63, vg = tid >> 6;
    float vacc[12];
    #pragma unroll
    for (int tt=0;tt<12;tt++) vacc[tt]=0.f;
    for (int k=0;k<7;k++){
        int v = vg + 4*k;
        if (v < 25){
            int s = shift_in[v*64+c];
            int base = (s&63)*300 + (s>>6);
            float wv = Wv[v];
            float tacc = 0.f;
            __hip_bfloat16* xo = x_perm + ((n*300+t0)*25 + v)*64 + c;
            #pragma unroll
            for (int tt=0;tt<12;tt++){
                __hip_bfloat16 hb = lx[base + tt*25];
                float val = __bfloat162float(hb);
                tacc += wt[tt]*val;
                vacc[tt] += wv*val;
                xo[tt*1600] = hb;
            }
            time_part[(n*25+tc)*1600 + c*25 + v] = tacc;
        }
    }
    #pragma unroll
    for (int tt=0;tt<12;tt++) red[vg][c][tt] = vacc[tt];
    __syncthreads();
    float vs=0.f, vq=0.f;
    for (int i = tid; i < 768; i += 256){
        int tt = i>>6, c2 = i&63;
        float tot = red[0][c2][tt]+red[1][c2][tt]+red[2][c2][tt]+red[3][c2][tt];
        view_pre[n*19200 + c2*300 + t0+tt] = tot;
        vs += tot; vq += tot*tot;
    }
    #pragma unroll
    for (int o=32;o>0;o>>=1){ vs += __shfl_down(vs,o); vq += __shfl_down(vq,o); }
    if ((tid&63)==0){ rs[(tid>>6)*2]=vs; rs[(tid>>6)*2+1]=vq; }
    __syncthreads();
    if (tid==0){
        view_part[(n*25+tc)*2]   = rs[0]+rs[2]+rs[4]+rs[6];
        view_part[(n*25+tc)*2+1] = rs[1]+rs[3]+rs[5]+rs[7];
    }
}

// K2a: reduce time partials over 25 chunks -> time_pre; block stat partials.
__global__ __launch_bounds__(256) void k2a_timereduce(
    const float* __restrict__ time_part, float* __restrict__ time_pre,
    float* __restrict__ tstat_part)
{
    int g = blockIdx.x*256 + threadIdx.x;   // [0, 102400)
    int n = g / 1600, r = g % 1600;
    float s = 0.f;
    for (int tc=0; tc<25; tc++) s += time_part[(n*25+tc)*1600 + r];
    time_pre[g] = s;
    float a = s, b = s*s;
    __shared__ float ls[8];
    #pragma unroll
    for (int o=32;o>0;o>>=1){ a += __shfl_down(a,o); b += __shfl_down(b,o); }
    int wid = threadIdx.x >> 6;
    if ((threadIdx.x & 63) == 0){ ls[wid*2] = a; ls[wid*2+1] = b; }
    __syncthreads();
    if (threadIdx.x == 0){
        tstat_part[blockIdx.x*2]   = ls[0]+ls[2]+ls[4]+ls[6];
        tstat_part[blockIdx.x*2+1] = ls[1]+ls[3]+ls[5]+ls[7];
    }
}

// K2b: final scalar BN stats for view/time branches.
__global__ __launch_bounds__(256) void k2b_finstats(
    const float* __restrict__ view_part, const float* __restrict__ tstat_part,
    float* __restrict__ fin)
{
    float acc[4] = {0.f,0.f,0.f,0.f};
    for (int i=threadIdx.x; i<1600; i+=256){ acc[0] += view_part[2*i]; acc[1] += view_part[2*i+1]; }
    for (int i=threadIdx.x; i<400;  i+=256){ acc[2] += tstat_part[2*i]; acc[3] += tstat_part[2*i+1]; }
    __shared__ float ls[4][4];
    int wid = threadIdx.x>>6, lane = threadIdx.x&63;
    #pragma unroll
    for (int j=0;j<4;j++){
        float a = acc[j];
        #pragma unroll
        for (int o=32;o>0;o>>=1) a += __shfl_down(a,o);
        if (lane==0) ls[j][wid] = a;
    }
    __syncthreads();
    if (threadIdx.x==0){
        float VS=ls[0][0]+ls[0][1]+ls[0][2]+ls[0][3];
        float VQ=ls[1][0]+ls[1][1]+ls[1][2]+ls[1][3];
        float TS=ls[2][0]+ls[2][1]+ls[2][2]+ls[2][3];
        float TQ=ls[3][0]+ls[3][1]+ls[3][2]+ls[3][3];
        float vm = VS / 1228800.f;
        float vvar = fmaxf(VQ/1228800.f - vm*vm, 0.f);
        float tm = TS / 102400.f;
        float tvar = fmaxf(TQ/102400.f - tm*tm, 0.f);
        fin[0] = vm; fin[1] = rsqrtf(vvar + EPS);
        fin[2] = tm; fin[3] = rsqrtf(tvar + EPS);
    }
}

// K3: sum2_raw[n,d,l] = sum_ch Ws[d,ch]*F(n, ch*325+l); per-d stat partials.
// Low-pressure version: wave w owns d = w*16..w*16+15 (wave-uniform), so
// Wst[ch][d] reads are LDS broadcasts; Ft[ch][lane] reads are stride-1.
__global__ __launch_bounds__(256) void k3_conv(
    const float* __restrict__ time_pre, const float* __restrict__ view_pre,
    const float* __restrict__ fin, const float* __restrict__ Ws,
    const float* __restrict__ g_t, const float* __restrict__ be_t,
    const float* __restrict__ g_v, const float* __restrict__ be_v,
    float* __restrict__ sum2_raw, float* __restrict__ chan_part)
{
    const int n = blockIdx.y, lc = blockIdx.x;
    const int tid = threadIdx.x, lane = tid & 63, w = tid >> 6;
    const int l = lc*64 + lane;
    __shared__ float Ft[64][64];    // [ch][l-lane]
    __shared__ float Wst[64][64];   // [ch][d]
    for (int i = tid; i < 4096; i += 256){
        int d = i>>6, ch = i&63;
        Wst[ch][d] = Ws[i];
    }
    const float vm = fin[0], vi = fin[1], tm = fin[2], ti = fin[3];
    const float gt = g_t[0]*ti, bt = be_t[0] - tm*g_t[0]*ti;
    const float gv = g_v[0]*vi, bv = be_v[0] - vm*g_v[0]*vi;
    const bool lval = (l < 325);
    for (int k=0;k<16;k++){
        int ch = w + 4*k;
        float val = 0.f;
        if (lval){
            int idx = ch*325 + l;
            if (idx < 1600) val = hsw(time_pre[n*1600 + idx]*gt + bt);
            else            val = hsw(view_pre[n*19200 + idx - 1600]*gv + bv);
        }
        Ft[ch][lane] = val;
    }
    __syncthreads();
    float acc[16];
    #pragma unroll
    for (int k=0;k<16;k++) acc[k]=0.f;
    const int d0 = w*16;
    #pragma unroll 4
    for (int ch=0; ch<64; ch++){
        float f = Ft[ch][lane];
        #pragma unroll
        for (int dd=0; dd<16; dd++)
            acc[dd] = fmaf(f, Wst[ch][d0+dd], acc[dd]);
    }
    #pragma unroll 1
    for (int dd=0; dd<16; dd++){
        int d = d0 + dd;
        float a = lval ? acc[dd] : 0.f;
        if (lval) sum2_raw[n*20800 + d*325 + l] = a;
        float s = a, q = a*a;
        #pragma unroll
        for (int o=32;o>0;o>>=1){ s += __shfl_down(s,o); q += __shfl_down(q,o); }
        if (lane == 0){
            int b = n*6 + lc;
            chan_part[b*128 + d*2]   = s;
            chan_part[b*128 + d*2+1] = q;
        }
    }
}

// K4: per-channel BN stats.
__global__ void k4_chanstats(const float* __restrict__ chan_part, float* __restrict__ chan_stats)
{
    int d = threadIdx.x;
    float S=0.f, Q=0.f;
    for (int b=0;b<384;b++){ S += chan_part[b*128 + d*2]; Q += chan_part[b*128 + d*2+1]; }
    float m = S/20800.f;
    float var = fmaxf(Q/20800.f - m*m, 0.f);
    chan_stats[d*2] = m;
    chan_stats[d*2+1] = rsqrtf(var + EPS);
}

// K5: xbar[d,l] = mean_n hswish(bn(sum2_raw)).
__global__ __launch_bounds__(256) void k5_xbar(
    const float* __restrict__ sum2_raw, const float* __restrict__ chan_stats,
    const float* __restrict__ g_s, const float* __restrict__ be_s,
    float* __restrict__ xbar)
{
    int g = blockIdx.x*256 + threadIdx.x;
    if (g >= 20800) return;
    int d = g / 325;
    float m = chan_stats[d*2], istd = chan_stats[d*2+1];
    float ga = g_s[d]*istd, bb = be_s[d] - m*ga;
    float acc = 0.f;
    for (int n=0;n<64;n++) acc += hsw(sum2_raw[n*20800 + g]*ga + bb);
    xbar[g] = acc * (1.f/64.f);
}

// K6: gates. l<300 -> x_time output (sigmoid); l>=300 -> scale[v][c]=tanh(sigmoid)+1.
__global__ __launch_bounds__(64) void k6_gates(
    const float* __restrict__ xbar, const float* __restrict__ W2t,
    const float* __restrict__ b2t, const float* __restrict__ W2v,
    const float* __restrict__ b2v, float* __restrict__ out_time,
    float* __restrict__ scale_vc)
{
    int l = blockIdx.x, tid = threadIdx.x;
    __shared__ float xb[64];
    xb[tid] = xbar[tid*325 + l];
    __syncthreads();
    if (l < 300){
        float acc = b2t[tid];
        for (int d=0; d<64; d++) acc += W2t[tid*64+d]*xb[d];
        out_time[tid*300 + l] = sigm(acc);
    } else {
        int v = l - 300;
        float acc = b2v[tid];
        for (int d=0; d<64; d++) acc += W2v[tid*64+d]*xb[d];
        scale_vc[v*64 + tid] = tanhf(sigm(acc)) + 1.f;
    }
}

// K7: y[r][d] = sum_c x_perm[r][c]*scale[r%25][c]*Lw[c][d], MFMA bf16.
// y aliases x_perm (in-place, row-disjoint across blocks; reads staged before writes).
__global__ __launch_bounds__(256) void k7_mfma(
    const __hip_bfloat16* __restrict__ x_perm, const float* __restrict__ scale_vc,
    const float* __restrict__ Lw, __hip_bfloat16* __restrict__ y)
{
    __shared__ __hip_bfloat16 As[256*64];
    __shared__ __hip_bfloat16 Bs[64*64];
    const int tid = threadIdx.x;
    const int row0 = blockIdx.x*256;
    // stage B^T (Bs[d][c] = Lw[c][d]) with XOR swizzle on 8-elem chunks
    for (int i = tid; i < 4096; i += 256){
        int d = i>>6, cc = i&63;
        int sw = (((cc>>3) ^ (d&7))<<3) + (cc&7);
        Bs[d*64 + sw] = __float2bfloat16(Lw[cc*64 + d]);
    }
    // stage A (scaled) with XOR swizzle
    for (int i = tid; i < 2048; i += 256){
        int row = i>>3, cc = i&7;
        int grow = row0 + row;
        int v = grow % 25;
        union { float4 f; unsigned short u[8]; } raw;
        raw.f = *reinterpret_cast<const float4*>(x_perm + grow*64 + cc*8);
        const float* sc = scale_vc + v*64 + cc*8;
        __hip_bfloat16 tmp[8];
        #pragma unroll
        for (int j=0;j<8;j++){
            float f = __uint_as_float((unsigned)raw.u[j] << 16);
            tmp[j] = __float2bfloat16(f * sc[j]);
        }
        int swc = (cc ^ (row&7))<<3;
        *reinterpret_cast<float4*>(&As[row*64 + swc]) = *reinterpret_cast<const float4*>(tmp);
    }
    __syncthreads();
    const int wave = tid>>6, lane = tid&63;
    const int lrow = lane&15, lk = lane>>4;
    f32x4 acc[4][4];
    #pragma unroll
    for (int mt=0;mt<4;mt++)
      #pragma unroll
      for (int nt=0;nt<4;nt++) acc[mt][nt] = (f32x4){0.f,0.f,0.f,0.f};
    #pragma unroll
    for (int ks=0;ks<2;ks++){
        bf16x8 a[4], b[4];
        int kc = ks*4 + lk;
        #pragma unroll
        for (int mt=0;mt<4;mt++){
            int row = wave*64 + mt*16 + lrow;
            a[mt] = *reinterpret_cast<const bf16x8*>(&As[row*64 + ((kc ^ (row&7))<<3)]);
        }
        #pragma unroll
        for (int nt=0;nt<4;nt++){
            int d = nt*16 + lrow;
            b[nt] = *reinterpret_cast<const bf16x8*>(&Bs[d*64 + ((kc ^ (d&7))<<3)]);
        }
        #pragma unroll
        for (int mt=0;mt<4;mt++)
          #pragma unroll
          for (int nt=0;nt<4;nt++)
            acc[mt][nt] = __builtin_amdgcn_mfma_f32_16x16x32_bf16(a[mt], b[nt], acc[mt][nt], 0, 0, 0);
    }
    #pragma unroll
    for (int mt=0;mt<4;mt++){
        int growb = row0 + wave*64 + mt*16 + lk*4;
        #pragma unroll
        for (int nt=0;nt<4;nt++){
            int col = nt*16 + lrow;
            #pragma unroll
            for (int j=0;j<4;j++)
                y[(growb + j)*64 + col] = __float2bfloat16(acc[mt][nt][j]);
        }
    }
}

// K8: per-column (sum, sumsq) partials of y over 120-row stripes.
__global__ __launch_bounds__(256) void k8_colpart(
    const __hip_bfloat16* __restrict__ y, float* __restrict__ col_part)
{
    const int b = blockIdx.x, tid = threadIdx.x;
    const int r0 = b*120;
    float s[7], q[7];
    #pragma unroll
    for (int k=0;k<7;k++){ s[k]=0.f; q[k]=0.f; }
    for (int r=r0; r<r0+120; r++){
        const __hip_bfloat16* yr = y + r*1600;
        #pragma unroll
        for (int k=0;k<7;k++){
            int col = tid + 256*k;
            if (col < 1600){
                float v = __bfloat162float(yr[col]);
                s[k] += v; q[k] += v*v;
            }
        }
    }
    #pragma unroll
    for (int k=0;k<7;k++){
        int col = tid + 256*k;
        if (col < 1600){
            col_part[b*3200 + col*2]   = s[k];
            col_part[b*3200 + col*2+1] = q[k];
        }
    }
}

// K8b: final per-column stats.
__global__ __launch_bounds__(256) void k8b_colstats(
    const float* __restrict__ col_part, float* __restrict__ col_stats)
{
    int col = blockIdx.x*256 + threadIdx.x;
    if (col >= 1600) return;
    float S=0.f, Q=0.f;
    for (int b=0;b<160;b++){ S += col_part[b*3200 + col*2]; Q += col_part[b*3200 + col*2+1]; }
    float m = S/19200.f;
    float var = fmaxf(Q/19200.f - m*m, 0.f);
    col_stats[col*2] = m;
    col_stats[col*2+1] = rsqrtf(var + EPS);
}

// K8c: fused per-j BN params: jP[j] = (A, B, bits(shift_out[j]), 0)
__global__ __launch_bounds__(256) void k8c_jparams(
    const int* __restrict__ shift_out, const float* __restrict__ col_stats,
    const float* __restrict__ g_bn, const float* __restrict__ be_bn,
    float4* __restrict__ jP)
{
    int j = blockIdx.x*256 + threadIdx.x;
    if (j >= 1600) return;
    int s = shift_out[j];
    float m = col_stats[s*2], istd = col_stats[s*2+1];
    float A = istd * g_bn[j];
    float B = be_bn[j] - m*A;
    jP[j] = make_float4(A, B, __int_as_float(s), 0.f);
}

// K9: stage 12 contiguous y rows in LDS, gather from LDS, coalesced x0/out.
__global__ __launch_bounds__(256) void k9_final(
    const float* __restrict__ x0, const __hip_bfloat16* __restrict__ y,
    const float4* __restrict__ jP, float* __restrict__ out)
{
    const int tc = blockIdx.x, n = blockIdx.y, t0 = tc*12;
    const int tid = threadIdx.x;
    __shared__ __hip_bfloat16 ys[19200];
    const __hip_bfloat16* yb = y + (n*300 + t0)*1600;
    for (int i = tid; i < 2400; i += 256)
        *reinterpret_cast<float4*>(&ys[i*8]) = *reinterpret_cast<const float4*>(yb + i*8);
    __syncthreads();
    const int base_x = n*480000 + t0*25;
    for (int k=0;k<75;k++){
        int e = k*256 + tid;
        int d = e/300;
        int rem = e - d*300;
        int tt = rem/25;
        int v = rem - tt*25;
        float4 p = jP[v*64 + d];
        int s = __float_as_int(p.z);
        float yv = __bfloat162float(ys[tt*1600 + s]);
        int idx = base_x + d*7500 + rem;
        out[idx] = fmaxf(fmaf(yv, p.x, p.y) + x0[idx], 0.f);
    }
}

extern "C" void kernel_launch(void* const* d_in, const int* in_sizes, int n_in,
                              void* d_out, int out_size, void* d_ws, size_t ws_size,
                              hipStream_t stream)
{
    const float* x0       = (const float*)d_in[0];
    const int*   shift_in = (const int*)d_in[1];
    const int*   shift_out= (const int*)d_in[2];
    const float* Wv       = (const float*)d_in[3];
    const float* g_v      = (const float*)d_in[5];
    const float* be_v     = (const float*)d_in[6];
    const float* Wt       = (const float*)d_in[7];
    const float* g_t      = (const float*)d_in[9];
    const float* be_t     = (const float*)d_in[10];
    const float* Ws       = (const float*)d_in[11];
    const float* g_s      = (const float*)d_in[13];
    const float* be_s     = (const float*)d_in[14];
    const float* W2t      = (const float*)d_in[15];
    const float* b2t      = (const float*)d_in[16];
    const float* W2v      = (const float*)d_in[17];
    const float* b2v      = (const float*)d_in[18];
    const float* Lw       = (const float*)d_in[19];
    const float* g_bn     = (const float*)d_in[21];
    const float* be_bn    = (const float*)d_in[22];
    // biases bv(4), bt(8), bs(12), Lb(20) cancel inside the following BNs.

    float* ws = (float*)d_ws;
    float* view_pre  = ws;                  // 1,228,800
    float* time_part = ws + 1228800;        // 2,560,000
    float* time_pre  = ws + 3788800;        //   102,400
    float* view_part = ws + 3891200;        //     3,200
    float* tstat_part= ws + 3894400;        //       800
    float* fin       = ws + 3895200;        //         8
    float* sum2_raw  = ws + 3895208;        // 1,331,200
    float* chan_part = ws + 5226408;        //    49,152
    float* chan_stats= ws + 5275560;        //       128
    float* xbar      = ws + 5275688;        //    20,800
    float* scale_vc  = ws + 5296488;        //     1,600
    float* col_part  = ws + 5298088;        //   512,000
    float* col_stats = ws + 5810088;        //     3,200
    float4* jP       = (float4*)(ws + 5813288); // 1,600 float4 (16B-aligned)
    __hip_bfloat16* x_perm = (__hip_bfloat16*)(ws + 5819688); // 30,720,000 bf16
    __hip_bfloat16* y = x_perm;             // in-place alias (row-wise 1:1)

    float* out      = (float*)d_out;
    float* out_time = out + 30720000;

    k1_viewtime   <<<dim3(25,64), 256, 0, stream>>>(x0, shift_in, Wv, Wt, view_pre, time_part, view_part, x_perm);
    k2a_timereduce<<<400, 256, 0, stream>>>(time_part, time_pre, tstat_part);
    k2b_finstats  <<<1, 256, 0, stream>>>(view_part, tstat_part, fin);
    k3_conv       <<<dim3(6,64), 256, 0, stream>>>(time_pre, view_pre, fin, Ws, g_t, be_t, g_v, be_v, sum2_raw, chan_part);
    k4_chanstats  <<<1, 64, 0, stream>>>(chan_part, chan_stats);
    k5_xbar       <<<82, 256, 0, stream>>>(sum2_raw, chan_stats, g_s, be_s, xbar);
    k6_gates      <<<325, 64, 0, stream>>>(xbar, W2t, b2t, W2v, b2v, out_time, scale_vc);
    k7_mfma       <<<1875, 256, 0, stream>>>(x_perm, scale_vc, Lw, y);
    k8_colpart    <<<160, 256, 0, stream>>>(y, col_part);
    k8b_colstats  <<<7, 256, 0, stream>>>(col_part, col_stats);
    k8c_jparams   <<<7, 256, 0, stream>>>(shift_out, col_stats, g_bn, be_bn, jP);
    k9_final      <<<dim3(25,64), 256, 0, stream>>>(x0, y, jP, out);
}

// Round 4
// 254.366 us; speedup vs baseline: 3.9496x; 1.4521x over previous
//
#include <hip/hip_runtime.h>
#include <hip/hip_bf16.h>

#define EPS 1e-5f

typedef __bf16 bf16x8 __attribute__((ext_vector_type(8)));
typedef float f32x4 __attribute__((ext_vector_type(4)));

__device__ __forceinline__ float hsw(float x){
    float t = fminf(fmaxf(x + 3.f, 0.f), 6.f);
    return x * t * (1.f/6.f);
}
__device__ __forceinline__ float sigm(float x){ return 1.f/(1.f + expf(-x)); }

// K1: stage x0[n,:,t0..t0+11,:] in LDS (coalesced), gather via shift_in from LDS,
// write x_perm[n,t,v,c] (bf16, coalesced), accumulate view/time conv partials.
__global__ __launch_bounds__(256) void k1_viewtime(
    const float* __restrict__ x0, const int* __restrict__ shift_in,
    const float* __restrict__ Wv, const float* __restrict__ Wt,
    float* __restrict__ view_pre, float* __restrict__ time_part,
    float* __restrict__ view_part, __hip_bfloat16* __restrict__ x_perm)
{
    const int tc = blockIdx.x, n = blockIdx.y, t0 = tc*12;
    const int tid = threadIdx.x;
    __shared__ __hip_bfloat16 lx[64*300];   // [c'][tt*25+v']
    __shared__ float red[4][64][12];
    __shared__ float rs[8];
    const float* xb = x0 + n*480000 + t0*25;
    for (int i = tid; i < 4800; i += 256){
        int row = i/75, c4 = i - row*75;
        float4 f = *reinterpret_cast<const float4*>(xb + row*7500 + c4*4);
        union { uint2 u; __hip_bfloat16 h[4]; } pk;
        pk.h[0]=__float2bfloat16(f.x); pk.h[1]=__float2bfloat16(f.y);
        pk.h[2]=__float2bfloat16(f.z); pk.h[3]=__float2bfloat16(f.w);
        *reinterpret_cast<uint2*>(&lx[row*300 + c4*4]) = pk.u;
    }
    float wt[12];
    #pragma unroll
    for (int tt=0;tt<12;tt++) wt[tt] = Wt[t0+tt];
    __syncthreads();
    const int c = tid & 63, vg = tid >> 6;
    float vacc[12];
    #pragma unroll
    for (int tt=0;tt<12;tt++) vacc[tt]=0.f;
    for (int k=0;k<7;k++){
        int v = vg + 4*k;
        if (v < 25){
            int s = shift_in[v*64+c];
            int base = (s&63)*300 + (s>>6);
            float wv = Wv[v];
            float tacc = 0.f;
            __hip_bfloat16* xo = x_perm + ((n*300+t0)*25 + v)*64 + c;
            #pragma unroll
            for (int tt=0;tt<12;tt++){
                __hip_bfloat16 hb = lx[base + tt*25];
                float val = __bfloat162float(hb);
                tacc += wt[tt]*val;
                vacc[tt] += wv*val;
                xo[tt*1600] = hb;
            }
            time_part[(n*25+tc)*1600 + c*25 + v] = tacc;
        }
    }
    #pragma unroll
    for (int tt=0;tt<12;tt++) red[vg][c][tt] = vacc[tt];
    __syncthreads();
    float vs=0.f, vq=0.f;
    for (int i = tid; i < 768; i += 256){
        int tt = i>>6, c2 = i&63;
        float tot = red[0][c2][tt]+red[1][c2][tt]+red[2][c2][tt]+red[3][c2][tt];
        view_pre[n*19200 + c2*300 + t0+tt] = tot;
        vs += tot; vq += tot*tot;
    }
    #pragma unroll
    for (int o=32;o>0;o>>=1){ vs += __shfl_down(vs,o); vq += __shfl_down(vq,o); }
    if ((tid&63)==0){ rs[(tid>>6)*2]=vs; rs[(tid>>6)*2+1]=vq; }
    __syncthreads();
    if (tid==0){
        view_part[(n*25+tc)*2]   = rs[0]+rs[2]+rs[4]+rs[6];
        view_part[(n*25+tc)*2+1] = rs[1]+rs[3]+rs[5]+rs[7];
    }
}

// K2a: reduce time partials over 25 chunks -> time_pre; block stat partials.
__global__ __launch_bounds__(256) void k2a_timereduce(
    const float* __restrict__ time_part, float* __restrict__ time_pre,
    float* __restrict__ tstat_part)
{
    int g = blockIdx.x*256 + threadIdx.x;   // [0, 102400)
    int n = g / 1600, r = g % 1600;
    float s = 0.f;
    for (int tc=0; tc<25; tc++) s += time_part[(n*25+tc)*1600 + r];
    time_pre[g] = s;
    float a = s, b = s*s;
    __shared__ float ls[8];
    #pragma unroll
    for (int o=32;o>0;o>>=1){ a += __shfl_down(a,o); b += __shfl_down(b,o); }
    int wid = threadIdx.x >> 6;
    if ((threadIdx.x & 63) == 0){ ls[wid*2] = a; ls[wid*2+1] = b; }
    __syncthreads();
    if (threadIdx.x == 0){
        tstat_part[blockIdx.x*2]   = ls[0]+ls[2]+ls[4]+ls[6];
        tstat_part[blockIdx.x*2+1] = ls[1]+ls[3]+ls[5]+ls[7];
    }
}

// K2b: final scalar BN stats for view/time branches.
__global__ __launch_bounds__(256) void k2b_finstats(
    const float* __restrict__ view_part, const float* __restrict__ tstat_part,
    float* __restrict__ fin)
{
    float acc[4] = {0.f,0.f,0.f,0.f};
    for (int i=threadIdx.x; i<1600; i+=256){ acc[0] += view_part[2*i]; acc[1] += view_part[2*i+1]; }
    for (int i=threadIdx.x; i<400;  i+=256){ acc[2] += tstat_part[2*i]; acc[3] += tstat_part[2*i+1]; }
    __shared__ float ls[4][4];
    int wid = threadIdx.x>>6, lane = threadIdx.x&63;
    #pragma unroll
    for (int j=0;j<4;j++){
        float a = acc[j];
        #pragma unroll
        for (int o=32;o>0;o>>=1) a += __shfl_down(a,o);
        if (lane==0) ls[j][wid] = a;
    }
    __syncthreads();
    if (threadIdx.x==0){
        float VS=ls[0][0]+ls[0][1]+ls[0][2]+ls[0][3];
        float VQ=ls[1][0]+ls[1][1]+ls[1][2]+ls[1][3];
        float TS=ls[2][0]+ls[2][1]+ls[2][2]+ls[2][3];
        float TQ=ls[3][0]+ls[3][1]+ls[3][2]+ls[3][3];
        float vm = VS / 1228800.f;
        float vvar = fmaxf(VQ/1228800.f - vm*vm, 0.f);
        float tm = TS / 102400.f;
        float tvar = fmaxf(TQ/102400.f - tm*tm, 0.f);
        fin[0] = vm; fin[1] = rsqrtf(vvar + EPS);
        fin[2] = tm; fin[3] = rsqrtf(tvar + EPS);
    }
}

// K3: sum2_raw[n,d,l] = sum_ch Ws[d,ch]*F(n, ch*325+l); per-d stat partials.
// Low-pressure version: wave w owns d = w*16..w*16+15 (wave-uniform), so
// Wst[ch][d] reads are LDS broadcasts; Ft[ch][lane] reads are stride-1.
__global__ __launch_bounds__(256) void k3_conv(
    const float* __restrict__ time_pre, const float* __restrict__ view_pre,
    const float* __restrict__ fin, const float* __restrict__ Ws,
    const float* __restrict__ g_t, const float* __restrict__ be_t,
    const float* __restrict__ g_v, const float* __restrict__ be_v,
    float* __restrict__ sum2_raw, float* __restrict__ chan_part)
{
    const int n = blockIdx.y, lc = blockIdx.x;
    const int tid = threadIdx.x, lane = tid & 63, w = tid >> 6;
    const int l = lc*64 + lane;
    __shared__ float Ft[64][64];    // [ch][l-lane]
    __shared__ float Wst[64][64];   // [ch][d]
    for (int i = tid; i < 4096; i += 256){
        int d = i>>6, ch = i&63;
        Wst[ch][d] = Ws[i];
    }
    const float vm = fin[0], vi = fin[1], tm = fin[2], ti = fin[3];
    const float gt = g_t[0]*ti, bt = be_t[0] - tm*g_t[0]*ti;
    const float gv = g_v[0]*vi, bv = be_v[0] - vm*g_v[0]*vi;
    const bool lval = (l < 325);
    for (int k=0;k<16;k++){
        int ch = w + 4*k;
        float val = 0.f;
        if (lval){
            int idx = ch*325 + l;
            if (idx < 1600) val = hsw(time_pre[n*1600 + idx]*gt + bt);
            else            val = hsw(view_pre[n*19200 + idx - 1600]*gv + bv);
        }
        Ft[ch][lane] = val;
    }
    __syncthreads();
    float acc[16];
    #pragma unroll
    for (int k=0;k<16;k++) acc[k]=0.f;
    const int d0 = w*16;
    #pragma unroll 4
    for (int ch=0; ch<64; ch++){
        float f = Ft[ch][lane];
        #pragma unroll
        for (int dd=0; dd<16; dd++)
            acc[dd] = fmaf(f, Wst[ch][d0+dd], acc[dd]);
    }
    #pragma unroll 1
    for (int dd=0; dd<16; dd++){
        int d = d0 + dd;
        float a = lval ? acc[dd] : 0.f;
        if (lval) sum2_raw[n*20800 + d*325 + l] = a;
        float s = a, q = a*a;
        #pragma unroll
        for (int o=32;o>0;o>>=1){ s += __shfl_down(s,o); q += __shfl_down(q,o); }
        if (lane == 0){
            int b = n*6 + lc;
            chan_part[b*128 + d*2]   = s;
            chan_part[b*128 + d*2+1] = q;
        }
    }
}

// K4: per-channel BN stats.
__global__ void k4_chanstats(const float* __restrict__ chan_part, float* __restrict__ chan_stats)
{
    int d = threadIdx.x;
    float S=0.f, Q=0.f;
    for (int b=0;b<384;b++){ S += chan_part[b*128 + d*2]; Q += chan_part[b*128 + d*2+1]; }
    float m = S/20800.f;
    float var = fmaxf(Q/20800.f - m*m, 0.f);
    chan_stats[d*2] = m;
    chan_stats[d*2+1] = rsqrtf(var + EPS);
}

// K5: xbar[d,l] = mean_n hswish(bn(sum2_raw)).
__global__ __launch_bounds__(256) void k5_xbar(
    const float* __restrict__ sum2_raw, const float* __restrict__ chan_stats,
    const float* __restrict__ g_s, const float* __restrict__ be_s,
    float* __restrict__ xbar)
{
    int g = blockIdx.x*256 + threadIdx.x;
    if (g >= 20800) return;
    int d = g / 325;
    float m = chan_stats[d*2], istd = chan_stats[d*2+1];
    float ga = g_s[d]*istd, bb = be_s[d] - m*ga;
    float acc = 0.f;
    for (int n=0;n<64;n++) acc += hsw(sum2_raw[n*20800 + g]*ga + bb);
    xbar[g] = acc * (1.f/64.f);
}

// K6: gates. l<300 -> x_time output (sigmoid); l>=300 -> scale[v][c]=tanh(sigmoid)+1.
__global__ __launch_bounds__(64) void k6_gates(
    const float* __restrict__ xbar, const float* __restrict__ W2t,
    const float* __restrict__ b2t, const float* __restrict__ W2v,
    const float* __restrict__ b2v, float* __restrict__ out_time,
    float* __restrict__ scale_vc)
{
    int l = blockIdx.x, tid = threadIdx.x;
    __shared__ float xb[64];
    xb[tid] = xbar[tid*325 + l];
    __syncthreads();
    if (l < 300){
        float acc = b2t[tid];
        for (int d=0; d<64; d++) acc += W2t[tid*64+d]*xb[d];
        out_time[tid*300 + l] = sigm(acc);
    } else {
        int v = l - 300;
        float acc = b2v[tid];
        for (int d=0; d<64; d++) acc += W2v[tid*64+d]*xb[d];
        scale_vc[v*64 + tid] = tanhf(sigm(acc)) + 1.f;
    }
}

// K7: y[r][d] = sum_c x_perm[r][c]*scale[r%25][c]*Lw[c][d], MFMA bf16.
// y aliases x_perm (in-place, row-disjoint across blocks; reads staged before writes).
__global__ __launch_bounds__(256) void k7_mfma(
    const __hip_bfloat16* __restrict__ x_perm, const float* __restrict__ scale_vc,
    const float* __restrict__ Lw, __hip_bfloat16* __restrict__ y)
{
    __shared__ __hip_bfloat16 As[256*64];
    __shared__ __hip_bfloat16 Bs[64*64];
    const int tid = threadIdx.x;
    const int row0 = blockIdx.x*256;
    // stage B^T (Bs[d][c] = Lw[c][d]) with XOR swizzle on 8-elem chunks
    for (int i = tid; i < 4096; i += 256){
        int d = i>>6, cc = i&63;
        int sw = (((cc>>3) ^ (d&7))<<3) + (cc&7);
        Bs[d*64 + sw] = __float2bfloat16(Lw[cc*64 + d]);
    }
    // stage A (scaled) with XOR swizzle
    for (int i = tid; i < 2048; i += 256){
        int row = i>>3, cc = i&7;
        int grow = row0 + row;
        int v = grow % 25;
        union { float4 f; unsigned short u[8]; } raw;
        raw.f = *reinterpret_cast<const float4*>(x_perm + grow*64 + cc*8);
        const float* sc = scale_vc + v*64 + cc*8;
        __hip_bfloat16 tmp[8];
        #pragma unroll
        for (int j=0;j<8;j++){
            float f = __uint_as_float((unsigned)raw.u[j] << 16);
            tmp[j] = __float2bfloat16(f * sc[j]);
        }
        int swc = (cc ^ (row&7))<<3;
        *reinterpret_cast<float4*>(&As[row*64 + swc]) = *reinterpret_cast<const float4*>(tmp);
    }
    __syncthreads();
    const int wave = tid>>6, lane = tid&63;
    const int lrow = lane&15, lk = lane>>4;
    f32x4 acc[4][4];
    #pragma unroll
    for (int mt=0;mt<4;mt++)
      #pragma unroll
      for (int nt=0;nt<4;nt++) acc[mt][nt] = (f32x4){0.f,0.f,0.f,0.f};
    #pragma unroll
    for (int ks=0;ks<2;ks++){
        bf16x8 a[4], b[4];
        int kc = ks*4 + lk;
        #pragma unroll
        for (int mt=0;mt<4;mt++){
            int row = wave*64 + mt*16 + lrow;
            a[mt] = *reinterpret_cast<const bf16x8*>(&As[row*64 + ((kc ^ (row&7))<<3)]);
        }
        #pragma unroll
        for (int nt=0;nt<4;nt++){
            int d = nt*16 + lrow;
            b[nt] = *reinterpret_cast<const bf16x8*>(&Bs[d*64 + ((kc ^ (d&7))<<3)]);
        }
        #pragma unroll
        for (int mt=0;mt<4;mt++)
          #pragma unroll
          for (int nt=0;nt<4;nt++)
            acc[mt][nt] = __builtin_amdgcn_mfma_f32_16x16x32_bf16(a[mt], b[nt], acc[mt][nt], 0, 0, 0);
    }
    #pragma unroll
    for (int mt=0;mt<4;mt++){
        int growb = row0 + wave*64 + mt*16 + lk*4;
        #pragma unroll
        for (int nt=0;nt<4;nt++){
            int col = nt*16 + lrow;
            #pragma unroll
            for (int j=0;j<4;j++)
                y[(growb + j)*64 + col] = __float2bfloat16(acc[mt][nt][j]);
        }
    }
}

// K8 v2: 1200 blocks x 16 rows; each thread owns 4-col chunks (uint2 loads).
// col_part layout: [400 chunks][1200 blocks][8 floats: s0..s3,q0..q3]
__global__ __launch_bounds__(256) void k8_colpart(
    const __hip_bfloat16* __restrict__ y, float* __restrict__ col_part)
{
    const int b = blockIdx.x, tid = threadIdx.x;
    const int r0 = b*16;
    const bool has2 = tid < 144;
    float s0[4]={0.f,0.f,0.f,0.f}, q0[4]={0.f,0.f,0.f,0.f};
    float s1[4]={0.f,0.f,0.f,0.f}, q1[4]={0.f,0.f,0.f,0.f};
    for (int r=r0; r<r0+16; r++){
        const __hip_bfloat16* yr = y + r*1600;
        uint2 u = *reinterpret_cast<const uint2*>(yr + tid*4);
        float a0 = __uint_as_float(u.x << 16);
        float a1 = __uint_as_float(u.x & 0xffff0000u);
        float a2 = __uint_as_float(u.y << 16);
        float a3 = __uint_as_float(u.y & 0xffff0000u);
        s0[0]+=a0; q0[0]+=a0*a0; s0[1]+=a1; q0[1]+=a1*a1;
        s0[2]+=a2; q0[2]+=a2*a2; s0[3]+=a3; q0[3]+=a3*a3;
        if (has2){
            uint2 w = *reinterpret_cast<const uint2*>(yr + (tid+256)*4);
            float b0 = __uint_as_float(w.x << 16);
            float b1 = __uint_as_float(w.x & 0xffff0000u);
            float b2 = __uint_as_float(w.y << 16);
            float b3 = __uint_as_float(w.y & 0xffff0000u);
            s1[0]+=b0; q1[0]+=b0*b0; s1[1]+=b1; q1[1]+=b1*b1;
            s1[2]+=b2; q1[2]+=b2*b2; s1[3]+=b3; q1[3]+=b3*b3;
        }
    }
    float* cp = col_part + (tid*1200 + b)*8;
    #pragma unroll
    for (int e=0;e<4;e++){ cp[e] = s0[e]; cp[4+e] = q0[e]; }
    if (has2){
        float* cp2 = col_part + ((tid+256)*1200 + b)*8;
        #pragma unroll
        for (int e=0;e<4;e++){ cp2[e] = s1[e]; cp2[4+e] = q1[e]; }
    }
}

// K8b v2: one block per 4-col chunk; reduce 1200 block-partials.
__global__ __launch_bounds__(256) void k8b_colstats(
    const float* __restrict__ col_part, float* __restrict__ col_stats)
{
    const int j = blockIdx.x, tid = threadIdx.x;
    float acc[8] = {0.f,0.f,0.f,0.f,0.f,0.f,0.f,0.f};
    for (int b = tid; b < 1200; b += 256){
        const float* cp = col_part + (j*1200 + b)*8;
        float4 x0 = *reinterpret_cast<const float4*>(cp);
        float4 x1 = *reinterpret_cast<const float4*>(cp+4);
        acc[0]+=x0.x; acc[1]+=x0.y; acc[2]+=x0.z; acc[3]+=x0.w;
        acc[4]+=x1.x; acc[5]+=x1.y; acc[6]+=x1.z; acc[7]+=x1.w;
    }
    #pragma unroll
    for (int e=0;e<8;e++){
        #pragma unroll
        for (int o=32;o>0;o>>=1) acc[e] += __shfl_down(acc[e], o);
    }
    __shared__ float red[4][8];
    if ((tid&63)==0){
        #pragma unroll
        for (int e=0;e<8;e++) red[tid>>6][e] = acc[e];
    }
    __syncthreads();
    if (tid < 4){
        float S = red[0][tid]+red[1][tid]+red[2][tid]+red[3][tid];
        float Q = red[0][4+tid]+red[1][4+tid]+red[2][4+tid]+red[3][4+tid];
        float m = S/19200.f;
        float var = fmaxf(Q/19200.f - m*m, 0.f);
        int col = j*4 + tid;
        col_stats[col*2]   = m;
        col_stats[col*2+1] = rsqrtf(var + EPS);
    }
}

// K8c: fused per-j BN params: jP[j] = (A, B, bits(shift_out[j]), 0)
__global__ __launch_bounds__(256) void k8c_jparams(
    const int* __restrict__ shift_out, const float* __restrict__ col_stats,
    const float* __restrict__ g_bn, const float* __restrict__ be_bn,
    float4* __restrict__ jP)
{
    int j = blockIdx.x*256 + threadIdx.x;
    if (j >= 1600) return;
    int s = shift_out[j];
    float m = col_stats[s*2], istd = col_stats[s*2+1];
    float A = istd * g_bn[j];
    float B = be_bn[j] - m*A;
    jP[j] = make_float4(A, B, __int_as_float(s), 0.f);
}

// K9: stage 12 contiguous y rows in LDS, gather from LDS, coalesced x0/out.
__global__ __launch_bounds__(256) void k9_final(
    const float* __restrict__ x0, const __hip_bfloat16* __restrict__ y,
    const float4* __restrict__ jP, float* __restrict__ out)
{
    const int tc = blockIdx.x, n = blockIdx.y, t0 = tc*12;
    const int tid = threadIdx.x;
    __shared__ __hip_bfloat16 ys[19200];
    const __hip_bfloat16* yb = y + (n*300 + t0)*1600;
    for (int i = tid; i < 2400; i += 256)
        *reinterpret_cast<float4*>(&ys[i*8]) = *reinterpret_cast<const float4*>(yb + i*8);
    __syncthreads();
    const int base_x = n*480000 + t0*25;
    for (int k=0;k<75;k++){
        int e = k*256 + tid;
        int d = e/300;
        int rem = e - d*300;
        int tt = rem/25;
        int v = rem - tt*25;
        float4 p = jP[v*64 + d];
        int s = __float_as_int(p.z);
        float yv = __bfloat162float(ys[tt*1600 + s]);
        int idx = base_x + d*7500 + rem;
        out[idx] = fmaxf(fmaf(yv, p.x, p.y) + x0[idx], 0.f);
    }
}

extern "C" void kernel_launch(void* const* d_in, const int* in_sizes, int n_in,
                              void* d_out, int out_size, void* d_ws, size_t ws_size,
                              hipStream_t stream)
{
    const float* x0       = (const float*)d_in[0];
    const int*   shift_in = (const int*)d_in[1];
    const int*   shift_out= (const int*)d_in[2];
    const float* Wv       = (const float*)d_in[3];
    const float* g_v      = (const float*)d_in[5];
    const float* be_v     = (const float*)d_in[6];
    const float* Wt       = (const float*)d_in[7];
    const float* g_t      = (const float*)d_in[9];
    const float* be_t     = (const float*)d_in[10];
    const float* Ws       = (const float*)d_in[11];
    const float* g_s      = (const float*)d_in[13];
    const float* be_s     = (const float*)d_in[14];
    const float* W2t      = (const float*)d_in[15];
    const float* b2t      = (const float*)d_in[16];
    const float* W2v      = (const float*)d_in[17];
    const float* b2v      = (const float*)d_in[18];
    const float* Lw       = (const float*)d_in[19];
    const float* g_bn     = (const float*)d_in[21];
    const float* be_bn    = (const float*)d_in[22];
    // biases bv(4), bt(8), bs(12), Lb(20) cancel inside the following BNs.

    float* ws = (float*)d_ws;
    float* view_pre  = ws;                  // 1,228,800  (dead after k3)
    float* time_part = ws + 1228800;        // 2,560,000  (dead after k2a)
    float* time_pre  = ws + 3788800;        //   102,400  (dead after k3)
    float* view_part = ws + 3891200;        //     3,200  (dead after k2b)
    float* tstat_part= ws + 3894400;        //       800
    float* fin       = ws + 3895200;        //         8
    float* sum2_raw  = ws + 3895208;        // 1,331,200
    float* chan_part = ws + 5226408;        //    49,152
    float* chan_stats= ws + 5275560;        //       128
    float* xbar      = ws + 5275688;        //    20,800
    float* scale_vc  = ws + 5296488;        //     1,600
    float* col_part  = ws;                  // 3,840,000 floats — ALIASES view_pre..time_pre (dead by k8)
    float* col_stats = ws + 5810088;        //     3,200
    float4* jP       = (float4*)(ws + 5813288); // 1,600 float4 (16B-aligned)
    __hip_bfloat16* x_perm = (__hip_bfloat16*)(ws + 5819688); // 30,720,000 bf16
    __hip_bfloat16* y = x_perm;             // in-place alias (row-wise 1:1)

    float* out      = (float*)d_out;
    float* out_time = out + 30720000;

    k1_viewtime   <<<dim3(25,64), 256, 0, stream>>>(x0, shift_in, Wv, Wt, view_pre, time_part, view_part, x_perm);
    k2a_timereduce<<<400, 256, 0, stream>>>(time_part, time_pre, tstat_part);
    k2b_finstats  <<<1, 256, 0, stream>>>(view_part, tstat_part, fin);
    k3_conv       <<<dim3(6,64), 256, 0, stream>>>(time_pre, view_pre, fin, Ws, g_t, be_t, g_v, be_v, sum2_raw, chan_part);
    k4_chanstats  <<<1, 64, 0, stream>>>(chan_part, chan_stats);
    k5_xbar       <<<82, 256, 0, stream>>>(sum2_raw, chan_stats, g_s, be_s, xbar);
    k6_gates      <<<325, 64, 0, stream>>>(xbar, W2t, b2t, W2v, b2v, out_time, scale_vc);
    k7_mfma       <<<1875, 256, 0, stream>>>(x_perm, scale_vc, Lw, y);
    k8_colpart    <<<1200, 256, 0, stream>>>(y, col_part);
    k8b_colstats  <<<400, 256, 0, stream>>>(col_part, col_stats);
    k8c_jparams   <<<7, 256, 0, stream>>>(shift_out, col_stats, g_bn, be_bn, jP);
    k9_final      <<<dim3(25,64), 256, 0, stream>>>(x0, y, jP, out);
}

// Round 5
// 246.668 us; speedup vs baseline: 4.0729x; 1.0312x over previous
//
#include <hip/hip_runtime.h>
#include <hip/hip_bf16.h>

#define EPS 1e-5f

typedef __bf16 bf16x8 __attribute__((ext_vector_type(8)));
typedef float f32x4 __attribute__((ext_vector_type(4)));

__device__ __forceinline__ float hsw(float x){
    float t = fminf(fmaxf(x + 3.f, 0.f), 6.f);
    return x * t * (1.f/6.f);
}
__device__ __forceinline__ float sigm(float x){ return 1.f/(1.f + expf(-x)); }

// K1: stage x0[n,:,t0..t0+11,:] in LDS (coalesced), gather via shift_in from LDS,
// write x_perm[n,t,v,c] (bf16, coalesced), accumulate view/time conv partials.
// lx padded 300->302: gather bank = (151c mod 32) -> all 32 banks (was 16).
__global__ __launch_bounds__(256) void k1_viewtime(
    const float* __restrict__ x0, const int* __restrict__ shift_in,
    const float* __restrict__ Wv, const float* __restrict__ Wt,
    float* __restrict__ view_pre, float* __restrict__ time_part,
    float* __restrict__ view_part, __hip_bfloat16* __restrict__ x_perm)
{
    const int tc = blockIdx.x, n = blockIdx.y, t0 = tc*12;
    const int tid = threadIdx.x;
    __shared__ __hip_bfloat16 lx[64*302];   // [c'][tt*25+v'], pad 2
    __shared__ float red[4][64][12];
    __shared__ float rs[8];
    const float* xb = x0 + n*480000 + t0*25;
    for (int i = tid; i < 4800; i += 256){
        int row = i/75, c4 = i - row*75;
        float4 f = *reinterpret_cast<const float4*>(xb + row*7500 + c4*4);
        union { uint2 u; __hip_bfloat16 h[4]; } pk;
        pk.h[0]=__float2bfloat16(f.x); pk.h[1]=__float2bfloat16(f.y);
        pk.h[2]=__float2bfloat16(f.z); pk.h[3]=__float2bfloat16(f.w);
        int base = row*302 + c4*4;           // even -> 4B aligned
        *reinterpret_cast<unsigned*>(&lx[base])   = pk.u.x;
        *reinterpret_cast<unsigned*>(&lx[base+2]) = pk.u.y;
    }
    float wt[12];
    #pragma unroll
    for (int tt=0;tt<12;tt++) wt[tt] = Wt[t0+tt];
    __syncthreads();
    const int c = tid & 63, vg = tid >> 6;
    float vacc[12];
    #pragma unroll
    for (int tt=0;tt<12;tt++) vacc[tt]=0.f;
    for (int k=0;k<7;k++){
        int v = vg + 4*k;
        if (v < 25){
            int s = shift_in[v*64+c];
            int base = (s&63)*302 + (s>>6);
            float wv = Wv[v];
            float tacc = 0.f;
            __hip_bfloat16* xo = x_perm + ((n*300+t0)*25 + v)*64 + c;
            #pragma unroll
            for (int tt=0;tt<12;tt++){
                __hip_bfloat16 hb = lx[base + tt*25];
                float val = __bfloat162float(hb);
                tacc += wt[tt]*val;
                vacc[tt] += wv*val;
                xo[tt*1600] = hb;
            }
            time_part[(n*25+tc)*1600 + c*25 + v] = tacc;
        }
    }
    #pragma unroll
    for (int tt=0;tt<12;tt++) red[vg][c][tt] = vacc[tt];
    __syncthreads();
    float vs=0.f, vq=0.f;
    for (int i = tid; i < 768; i += 256){
        int tt = i>>6, c2 = i&63;
        float tot = red[0][c2][tt]+red[1][c2][tt]+red[2][c2][tt]+red[3][c2][tt];
        view_pre[n*19200 + c2*300 + t0+tt] = tot;
        vs += tot; vq += tot*tot;
    }
    #pragma unroll
    for (int o=32;o>0;o>>=1){ vs += __shfl_down(vs,o); vq += __shfl_down(vq,o); }
    if ((tid&63)==0){ rs[(tid>>6)*2]=vs; rs[(tid>>6)*2+1]=vq; }
    __syncthreads();
    if (tid==0){
        view_part[(n*25+tc)*2]   = rs[0]+rs[2]+rs[4]+rs[6];
        view_part[(n*25+tc)*2+1] = rs[1]+rs[3]+rs[5]+rs[7];
    }
}

// K2a: reduce time partials over 25 chunks -> time_pre; block stat partials.
__global__ __launch_bounds__(256) void k2a_timereduce(
    const float* __restrict__ time_part, float* __restrict__ time_pre,
    float* __restrict__ tstat_part)
{
    int g = blockIdx.x*256 + threadIdx.x;   // [0, 102400)
    int n = g / 1600, r = g % 1600;
    float s = 0.f;
    for (int tc=0; tc<25; tc++) s += time_part[(n*25+tc)*1600 + r];
    time_pre[g] = s;
    float a = s, b = s*s;
    __shared__ float ls[8];
    #pragma unroll
    for (int o=32;o>0;o>>=1){ a += __shfl_down(a,o); b += __shfl_down(b,o); }
    int wid = threadIdx.x >> 6;
    if ((threadIdx.x & 63) == 0){ ls[wid*2] = a; ls[wid*2+1] = b; }
    __syncthreads();
    if (threadIdx.x == 0){
        tstat_part[blockIdx.x*2]   = ls[0]+ls[2]+ls[4]+ls[6];
        tstat_part[blockIdx.x*2+1] = ls[1]+ls[3]+ls[5]+ls[7];
    }
}

// K2b: final scalar BN stats for view/time branches.
__global__ __launch_bounds__(256) void k2b_finstats(
    const float* __restrict__ view_part, const float* __restrict__ tstat_part,
    float* __restrict__ fin)
{
    float acc[4] = {0.f,0.f,0.f,0.f};
    for (int i=threadIdx.x; i<1600; i+=256){ acc[0] += view_part[2*i]; acc[1] += view_part[2*i+1]; }
    for (int i=threadIdx.x; i<400;  i+=256){ acc[2] += tstat_part[2*i]; acc[3] += tstat_part[2*i+1]; }
    __shared__ float ls[4][4];
    int wid = threadIdx.x>>6, lane = threadIdx.x&63;
    #pragma unroll
    for (int j=0;j<4;j++){
        float a = acc[j];
        #pragma unroll
        for (int o=32;o>0;o>>=1) a += __shfl_down(a,o);
        if (lane==0) ls[j][wid] = a;
    }
    __syncthreads();
    if (threadIdx.x==0){
        float VS=ls[0][0]+ls[0][1]+ls[0][2]+ls[0][3];
        float VQ=ls[1][0]+ls[1][1]+ls[1][2]+ls[1][3];
        float TS=ls[2][0]+ls[2][1]+ls[2][2]+ls[2][3];
        float TQ=ls[3][0]+ls[3][1]+ls[3][2]+ls[3][3];
        float vm = VS / 1228800.f;
        float vvar = fmaxf(VQ/1228800.f - vm*vm, 0.f);
        float tm = TS / 102400.f;
        float tvar = fmaxf(TQ/102400.f - tm*tm, 0.f);
        fin[0] = vm; fin[1] = rsqrtf(vvar + EPS);
        fin[2] = tm; fin[3] = rsqrtf(tvar + EPS);
    }
}

// K3: sum2_raw[n,d,l] = sum_ch Ws[d,ch]*F(n, ch*325+l); per-d stat partials.
__global__ __launch_bounds__(256) void k3_conv(
    const float* __restrict__ time_pre, const float* __restrict__ view_pre,
    const float* __restrict__ fin, const float* __restrict__ Ws,
    const float* __restrict__ g_t, const float* __restrict__ be_t,
    const float* __restrict__ g_v, const float* __restrict__ be_v,
    float* __restrict__ sum2_raw, float* __restrict__ chan_part)
{
    const int n = blockIdx.y, lc = blockIdx.x;
    const int tid = threadIdx.x, lane = tid & 63, w = tid >> 6;
    const int l = lc*64 + lane;
    __shared__ float Ft[64][64];    // [ch][l-lane]
    __shared__ float Wst[64][64];   // [ch][d]
    for (int i = tid; i < 4096; i += 256){
        int d = i>>6, ch = i&63;
        Wst[ch][d] = Ws[i];
    }
    const float vm = fin[0], vi = fin[1], tm = fin[2], ti = fin[3];
    const float gt = g_t[0]*ti, bt = be_t[0] - tm*g_t[0]*ti;
    const float gv = g_v[0]*vi, bv = be_v[0] - vm*g_v[0]*vi;
    const bool lval = (l < 325);
    for (int k=0;k<16;k++){
        int ch = w + 4*k;
        float val = 0.f;
        if (lval){
            int idx = ch*325 + l;
            if (idx < 1600) val = hsw(time_pre[n*1600 + idx]*gt + bt);
            else            val = hsw(view_pre[n*19200 + idx - 1600]*gv + bv);
        }
        Ft[ch][lane] = val;
    }
    __syncthreads();
    float acc[16];
    #pragma unroll
    for (int k=0;k<16;k++) acc[k]=0.f;
    const int d0 = w*16;
    #pragma unroll 4
    for (int ch=0; ch<64; ch++){
        float f = Ft[ch][lane];
        #pragma unroll
        for (int dd=0; dd<16; dd++)
            acc[dd] = fmaf(f, Wst[ch][d0+dd], acc[dd]);
    }
    #pragma unroll 1
    for (int dd=0; dd<16; dd++){
        int d = d0 + dd;
        float a = lval ? acc[dd] : 0.f;
        if (lval) sum2_raw[n*20800 + d*325 + l] = a;
        float s = a, q = a*a;
        #pragma unroll
        for (int o=32;o>0;o>>=1){ s += __shfl_down(s,o); q += __shfl_down(q,o); }
        if (lane == 0){
            int b = n*6 + lc;
            chan_part[b*128 + d*2]   = s;
            chan_part[b*128 + d*2+1] = q;
        }
    }
}

// K4: per-channel BN stats.
__global__ void k4_chanstats(const float* __restrict__ chan_part, float* __restrict__ chan_stats)
{
    int d = threadIdx.x;
    float S=0.f, Q=0.f;
    for (int b=0;b<384;b++){ S += chan_part[b*128 + d*2]; Q += chan_part[b*128 + d*2+1]; }
    float m = S/20800.f;
    float var = fmaxf(Q/20800.f - m*m, 0.f);
    chan_stats[d*2] = m;
    chan_stats[d*2+1] = rsqrtf(var + EPS);
}

// K5: xbar[d,l] = mean_n hswish(bn(sum2_raw)).
__global__ __launch_bounds__(256) void k5_xbar(
    const float* __restrict__ sum2_raw, const float* __restrict__ chan_stats,
    const float* __restrict__ g_s, const float* __restrict__ be_s,
    float* __restrict__ xbar)
{
    int g = blockIdx.x*256 + threadIdx.x;
    if (g >= 20800) return;
    int d = g / 325;
    float m = chan_stats[d*2], istd = chan_stats[d*2+1];
    float ga = g_s[d]*istd, bb = be_s[d] - m*ga;
    float acc = 0.f;
    for (int n=0;n<64;n++) acc += hsw(sum2_raw[n*20800 + g]*ga + bb);
    xbar[g] = acc * (1.f/64.f);
}

// K6: gates. l<300 -> x_time output (sigmoid); l>=300 -> scale[v][c]=tanh(sigmoid)+1.
__global__ __launch_bounds__(64) void k6_gates(
    const float* __restrict__ xbar, const float* __restrict__ W2t,
    const float* __restrict__ b2t, const float* __restrict__ W2v,
    const float* __restrict__ b2v, float* __restrict__ out_time,
    float* __restrict__ scale_vc)
{
    int l = blockIdx.x, tid = threadIdx.x;
    __shared__ float xb[64];
    xb[tid] = xbar[tid*325 + l];
    __syncthreads();
    if (l < 300){
        float acc = b2t[tid];
        for (int d=0; d<64; d++) acc += W2t[tid*64+d]*xb[d];
        out_time[tid*300 + l] = sigm(acc);
    } else {
        int v = l - 300;
        float acc = b2v[tid];
        for (int d=0; d<64; d++) acc += W2v[tid*64+d]*xb[d];
        scale_vc[v*64 + tid] = tanhf(sigm(acc)) + 1.f;
    }
}

// K7: y[r][d] = sum_c x_perm[r][c]*scale[r%25][c]*Lw[c][d], MFMA bf16.
__global__ __launch_bounds__(256) void k7_mfma(
    const __hip_bfloat16* __restrict__ x_perm, const float* __restrict__ scale_vc,
    const float* __restrict__ Lw, __hip_bfloat16* __restrict__ y)
{
    __shared__ __hip_bfloat16 As[256*64];
    __shared__ __hip_bfloat16 Bs[64*64];
    const int tid = threadIdx.x;
    const int row0 = blockIdx.x*256;
    for (int i = tid; i < 4096; i += 256){
        int d = i>>6, cc = i&63;
        int sw = (((cc>>3) ^ (d&7))<<3) + (cc&7);
        Bs[d*64 + sw] = __float2bfloat16(Lw[cc*64 + d]);
    }
    for (int i = tid; i < 2048; i += 256){
        int row = i>>3, cc = i&7;
        int grow = row0 + row;
        int v = grow % 25;
        union { float4 f; unsigned short u[8]; } raw;
        raw.f = *reinterpret_cast<const float4*>(x_perm + grow*64 + cc*8);
        const float* sc = scale_vc + v*64 + cc*8;
        __hip_bfloat16 tmp[8];
        #pragma unroll
        for (int j=0;j<8;j++){
            float f = __uint_as_float((unsigned)raw.u[j] << 16);
            tmp[j] = __float2bfloat16(f * sc[j]);
        }
        int swc = (cc ^ (row&7))<<3;
        *reinterpret_cast<float4*>(&As[row*64 + swc]) = *reinterpret_cast<const float4*>(tmp);
    }
    __syncthreads();
    const int wave = tid>>6, lane = tid&63;
    const int lrow = lane&15, lk = lane>>4;
    f32x4 acc[4][4];
    #pragma unroll
    for (int mt=0;mt<4;mt++)
      #pragma unroll
      for (int nt=0;nt<4;nt++) acc[mt][nt] = (f32x4){0.f,0.f,0.f,0.f};
    #pragma unroll
    for (int ks=0;ks<2;ks++){
        bf16x8 a[4], b[4];
        int kc = ks*4 + lk;
        #pragma unroll
        for (int mt=0;mt<4;mt++){
            int row = wave*64 + mt*16 + lrow;
            a[mt] = *reinterpret_cast<const bf16x8*>(&As[row*64 + ((kc ^ (row&7))<<3)]);
        }
        #pragma unroll
        for (int nt=0;nt<4;nt++){
            int d = nt*16 + lrow;
            b[nt] = *reinterpret_cast<const bf16x8*>(&Bs[d*64 + ((kc ^ (d&7))<<3)]);
        }
        #pragma unroll
        for (int mt=0;mt<4;mt++)
          #pragma unroll
          for (int nt=0;nt<4;nt++)
            acc[mt][nt] = __builtin_amdgcn_mfma_f32_16x16x32_bf16(a[mt], b[nt], acc[mt][nt], 0, 0, 0);
    }
    #pragma unroll
    for (int mt=0;mt<4;mt++){
        int growb = row0 + wave*64 + mt*16 + lk*4;
        #pragma unroll
        for (int nt=0;nt<4;nt++){
            int col = nt*16 + lrow;
            #pragma unroll
            for (int j=0;j<4;j++)
                y[(growb + j)*64 + col] = __float2bfloat16(acc[mt][nt][j]);
        }
    }
}

// K8 v2: 1200 blocks x 16 rows; each thread owns 4-col chunks (uint2 loads).
__global__ __launch_bounds__(256) void k8_colpart(
    const __hip_bfloat16* __restrict__ y, float* __restrict__ col_part)
{
    const int b = blockIdx.x, tid = threadIdx.x;
    const int r0 = b*16;
    const bool has2 = tid < 144;
    float s0[4]={0.f,0.f,0.f,0.f}, q0[4]={0.f,0.f,0.f,0.f};
    float s1[4]={0.f,0.f,0.f,0.f}, q1[4]={0.f,0.f,0.f,0.f};
    for (int r=r0; r<r0+16; r++){
        const __hip_bfloat16* yr = y + r*1600;
        uint2 u = *reinterpret_cast<const uint2*>(yr + tid*4);
        float a0 = __uint_as_float(u.x << 16);
        float a1 = __uint_as_float(u.x & 0xffff0000u);
        float a2 = __uint_as_float(u.y << 16);
        float a3 = __uint_as_float(u.y & 0xffff0000u);
        s0[0]+=a0; q0[0]+=a0*a0; s0[1]+=a1; q0[1]+=a1*a1;
        s0[2]+=a2; q0[2]+=a2*a2; s0[3]+=a3; q0[3]+=a3*a3;
        if (has2){
            uint2 w = *reinterpret_cast<const uint2*>(yr + (tid+256)*4);
            float b0 = __uint_as_float(w.x << 16);
            float b1 = __uint_as_float(w.x & 0xffff0000u);
            float b2 = __uint_as_float(w.y << 16);
            float b3 = __uint_as_float(w.y & 0xffff0000u);
            s1[0]+=b0; q1[0]+=b0*b0; s1[1]+=b1; q1[1]+=b1*b1;
            s1[2]+=b2; q1[2]+=b2*b2; s1[3]+=b3; q1[3]+=b3*b3;
        }
    }
    float* cp = col_part + (tid*1200 + b)*8;
    #pragma unroll
    for (int e=0;e<4;e++){ cp[e] = s0[e]; cp[4+e] = q0[e]; }
    if (has2){
        float* cp2 = col_part + ((tid+256)*1200 + b)*8;
        #pragma unroll
        for (int e=0;e<4;e++){ cp2[e] = s1[e]; cp2[4+e] = q1[e]; }
    }
}

// K8b v2: one block per 4-col chunk; reduce 1200 block-partials.
__global__ __launch_bounds__(256) void k8b_colstats(
    const float* __restrict__ col_part, float* __restrict__ col_stats)
{
    const int j = blockIdx.x, tid = threadIdx.x;
    float acc[8] = {0.f,0.f,0.f,0.f,0.f,0.f,0.f,0.f};
    for (int b = tid; b < 1200; b += 256){
        const float* cp = col_part + (j*1200 + b)*8;
        float4 x0 = *reinterpret_cast<const float4*>(cp);
        float4 x1 = *reinterpret_cast<const float4*>(cp+4);
        acc[0]+=x0.x; acc[1]+=x0.y; acc[2]+=x0.z; acc[3]+=x0.w;
        acc[4]+=x1.x; acc[5]+=x1.y; acc[6]+=x1.z; acc[7]+=x1.w;
    }
    #pragma unroll
    for (int e=0;e<8;e++){
        #pragma unroll
        for (int o=32;o>0;o>>=1) acc[e] += __shfl_down(acc[e], o);
    }
    __shared__ float red[4][8];
    if ((tid&63)==0){
        #pragma unroll
        for (int e=0;e<8;e++) red[tid>>6][e] = acc[e];
    }
    __syncthreads();
    if (tid < 4){
        float S = red[0][tid]+red[1][tid]+red[2][tid]+red[3][tid];
        float Q = red[0][4+tid]+red[1][4+tid]+red[2][4+tid]+red[3][4+tid];
        float m = S/19200.f;
        float var = fmaxf(Q/19200.f - m*m, 0.f);
        int col = j*4 + tid;
        col_stats[col*2]   = m;
        col_stats[col*2+1] = rsqrtf(var + EPS);
    }
}

// K8c: fused per-j BN params: jP[j] = (A, B, bits(shift_out[j]), 0)
__global__ __launch_bounds__(256) void k8c_jparams(
    const int* __restrict__ shift_out, const float* __restrict__ col_stats,
    const float* __restrict__ g_bn, const float* __restrict__ be_bn,
    float4* __restrict__ jP)
{
    int j = blockIdx.x*256 + threadIdx.x;
    if (j >= 1600) return;
    int s = shift_out[j];
    float m = col_stats[s*2], istd = col_stats[s*2+1];
    float A = istd * g_bn[j];
    float B = be_bn[j] - m*A;
    jP[j] = make_float4(A, B, __int_as_float(s), 0.f);
}

// K9: stage 12 y rows in LDS with XOR swizzle (kills the 25-way bank conflict
// on the shift_out gather: s = 64*((v-d)%25)+d -> same bank for all v without
// swizzle). float4 x0/out access.
__global__ __launch_bounds__(256) void k9_final(
    const float* __restrict__ x0, const __hip_bfloat16* __restrict__ y,
    const float4* __restrict__ jP, float* __restrict__ out)
{
    const int tc = blockIdx.x, n = blockIdx.y, t0 = tc*12;
    const int tid = threadIdx.x;
    __shared__ __hip_bfloat16 ys[19200];
    const __hip_bfloat16* yb = y + (n*300 + t0)*1600;
    for (int i = tid; i < 4800; i += 256){
        int e = i*4;
        int es = e ^ (((e>>6)&15)<<2);    // swizzle bits 3..5? no: bits 2..5 xor bits 6..9
        *reinterpret_cast<uint2*>(&ys[es]) = *reinterpret_cast<const uint2*>(yb + e);
    }
    __syncthreads();
    const int base_x = n*480000 + t0*25;
    for (int k=0;k<19;k++){
        int e2 = k*256 + tid;
        if (e2 >= 4800) break;
        int d  = e2/75;
        int ch = e2 - d*75;
        int rem0 = ch*4;
        const int gidx = base_x + d*7500 + rem0;
        float4 xv = *reinterpret_cast<const float4*>(x0 + gidx);
        float ovv[4];
        float xvv[4] = {xv.x, xv.y, xv.z, xv.w};
        #pragma unroll
        for (int j=0;j<4;j++){
            int rem = rem0 + j;
            int tt = rem/25;
            int v  = rem - tt*25;
            float4 p = jP[v*64 + d];
            int s = __float_as_int(p.z);
            int e3 = tt*1600 + s;
            int es3 = e3 ^ (((e3>>6)&15)<<2);
            float yv = __bfloat162float(ys[es3]);
            ovv[j] = fmaxf(fmaf(yv, p.x, p.y) + xvv[j], 0.f);
        }
        float4 ov = {ovv[0], ovv[1], ovv[2], ovv[3]};
        *reinterpret_cast<float4*>(out + gidx) = ov;
    }
}

extern "C" void kernel_launch(void* const* d_in, const int* in_sizes, int n_in,
                              void* d_out, int out_size, void* d_ws, size_t ws_size,
                              hipStream_t stream)
{
    const float* x0       = (const float*)d_in[0];
    const int*   shift_in = (const int*)d_in[1];
    const int*   shift_out= (const int*)d_in[2];
    const float* Wv       = (const float*)d_in[3];
    const float* g_v      = (const float*)d_in[5];
    const float* be_v     = (const float*)d_in[6];
    const float* Wt       = (const float*)d_in[7];
    const float* g_t      = (const float*)d_in[9];
    const float* be_t     = (const float*)d_in[10];
    const float* Ws       = (const float*)d_in[11];
    const float* g_s      = (const float*)d_in[13];
    const float* be_s     = (const float*)d_in[14];
    const float* W2t      = (const float*)d_in[15];
    const float* b2t      = (const float*)d_in[16];
    const float* W2v      = (const float*)d_in[17];
    const float* b2v      = (const float*)d_in[18];
    const float* Lw       = (const float*)d_in[19];
    const float* g_bn     = (const float*)d_in[21];
    const float* be_bn    = (const float*)d_in[22];

    float* ws = (float*)d_ws;
    float* view_pre  = ws;                  // 1,228,800  (dead after k3)
    float* time_part = ws + 1228800;        // 2,560,000  (dead after k2a)
    float* time_pre  = ws + 3788800;        //   102,400  (dead after k3)
    float* view_part = ws + 3891200;        //     3,200  (dead after k2b)
    float* tstat_part= ws + 3894400;        //       800
    float* fin       = ws + 3895200;        //         8
    float* sum2_raw  = ws + 3895208;        // 1,331,200
    float* chan_part = ws + 5226408;        //    49,152
    float* chan_stats= ws + 5275560;        //       128
    float* xbar      = ws + 5275688;        //    20,800
    float* scale_vc  = ws + 5296488;        //     1,600
    float* col_part  = ws;                  // 3,840,000 floats — ALIASES view_pre..time_pre (dead by k8)
    float* col_stats = ws + 5810088;        //     3,200
    float4* jP       = (float4*)(ws + 5813288); // 1,600 float4 (16B-aligned)
    __hip_bfloat16* x_perm = (__hip_bfloat16*)(ws + 5819688); // 30,720,000 bf16
    __hip_bfloat16* y = x_perm;             // in-place alias (row-wise 1:1)

    float* out      = (float*)d_out;
    float* out_time = out + 30720000;

    k1_viewtime   <<<dim3(25,64), 256, 0, stream>>>(x0, shift_in, Wv, Wt, view_pre, time_part, view_part, x_perm);
    k2a_timereduce<<<400, 256, 0, stream>>>(time_part, time_pre, tstat_part);
    k2b_finstats  <<<1, 256, 0, stream>>>(view_part, tstat_part, fin);
    k3_conv       <<<dim3(6,64), 256, 0, stream>>>(time_pre, view_pre, fin, Ws, g_t, be_t, g_v, be_v, sum2_raw, chan_part);
    k4_chanstats  <<<1, 64, 0, stream>>>(chan_part, chan_stats);
    k5_xbar       <<<82, 256, 0, stream>>>(sum2_raw, chan_stats, g_s, be_s, xbar);
    k6_gates      <<<325, 64, 0, stream>>>(xbar, W2t, b2t, W2v, b2v, out_time, scale_vc);
    k7_mfma       <<<1875, 256, 0, stream>>>(x_perm, scale_vc, Lw, y);
    k8_colpart    <<<1200, 256, 0, stream>>>(y, col_part);
    k8b_colstats  <<<400, 256, 0, stream>>>(col_part, col_stats);
    k8c_jparams   <<<7, 256, 0, stream>>>(shift_out, col_stats, g_bn, be_bn, jP);
    k9_final      <<<dim3(25,64), 256, 0, stream>>>(x0, y, jP, out);
}

// Round 6
// 224.332 us; speedup vs baseline: 4.4784x; 1.0996x over previous
//
#include <hip/hip_runtime.h>
#include <hip/hip_bf16.h>

#define EPS 1e-5f

typedef __bf16 bf16x8 __attribute__((ext_vector_type(8)));
typedef float f32x4 __attribute__((ext_vector_type(4)));

__device__ __forceinline__ float hsw(float x){
    float t = fminf(fmaxf(x + 3.f, 0.f), 6.f);
    return x * t * (1.f/6.f);
}
__device__ __forceinline__ float sigm(float x){ return 1.f/(1.f + expf(-x)); }

// K1: stage x0[n,:,t0..t0+11,:] in LDS (coalesced), gather via shift_in from LDS,
// write x_perm[n,t,v,c] (bf16, coalesced), accumulate view/time conv partials.
// red buffer aliases lx (dead after the v-loop) -> LDS 38.7KB -> 4 blocks/CU.
__global__ __launch_bounds__(256) void k1_viewtime(
    const float* __restrict__ x0, const int* __restrict__ shift_in,
    const float* __restrict__ Wv, const float* __restrict__ Wt,
    float* __restrict__ view_pre, float* __restrict__ time_part,
    float* __restrict__ view_part, __hip_bfloat16* __restrict__ x_perm)
{
    const int tc = blockIdx.x, n = blockIdx.y, t0 = tc*12;
    const int tid = threadIdx.x;
    __shared__ alignas(16) unsigned char smem[64*302*2];   // 38656 B
    __shared__ float rs[8];
    __hip_bfloat16* lx = (__hip_bfloat16*)smem;             // [c'][tt*25+v'], stride 302
    float* red = (float*)smem;                              // [w*64+c][13] after lx dead
    const float* xb = x0 + n*480000 + t0*25;
    for (int i = tid; i < 4800; i += 256){
        int row = i/75, c4 = i - row*75;
        float4 f = *reinterpret_cast<const float4*>(xb + row*7500 + c4*4);
        union { uint2 u; __hip_bfloat16 h[4]; } pk;
        pk.h[0]=__float2bfloat16(f.x); pk.h[1]=__float2bfloat16(f.y);
        pk.h[2]=__float2bfloat16(f.z); pk.h[3]=__float2bfloat16(f.w);
        int base = row*302 + c4*4;
        *reinterpret_cast<unsigned*>(&lx[base])   = pk.u.x;
        *reinterpret_cast<unsigned*>(&lx[base+2]) = pk.u.y;
    }
    float wt[12];
    #pragma unroll
    for (int tt=0;tt<12;tt++) wt[tt] = Wt[t0+tt];
    __syncthreads();
    const int c = tid & 63, vg = tid >> 6;
    float vacc[12];
    #pragma unroll
    for (int tt=0;tt<12;tt++) vacc[tt]=0.f;
    for (int k=0;k<7;k++){
        int v = vg + 4*k;
        if (v < 25){
            int s = shift_in[v*64+c];
            int base = (s&63)*302 + (s>>6);
            float wv = Wv[v];
            float tacc = 0.f;
            __hip_bfloat16* xo = x_perm + ((n*300+t0)*25 + v)*64 + c;
            #pragma unroll
            for (int tt=0;tt<12;tt++){
                __hip_bfloat16 hb = lx[base + tt*25];
                float val = __bfloat162float(hb);
                tacc += wt[tt]*val;
                vacc[tt] += wv*val;
                xo[tt*1600] = hb;
            }
            time_part[(n*25+tc)*1600 + c*25 + v] = tacc;
        }
    }
    __syncthreads();     // all lx reads done; safe to reuse smem as red
    #pragma unroll
    for (int tt=0;tt<12;tt++) red[(vg*64+c)*13 + tt] = vacc[tt];
    __syncthreads();
    float vs=0.f, vq=0.f;
    for (int i = tid; i < 768; i += 256){
        int tt = i>>6, c2 = i&63;
        float tot = red[(0*64+c2)*13+tt]+red[(1*64+c2)*13+tt]
                  + red[(2*64+c2)*13+tt]+red[(3*64+c2)*13+tt];
        view_pre[n*19200 + c2*300 + t0+tt] = tot;
        vs += tot; vq += tot*tot;
    }
    #pragma unroll
    for (int o=32;o>0;o>>=1){ vs += __shfl_down(vs,o); vq += __shfl_down(vq,o); }
    if ((tid&63)==0){ rs[(tid>>6)*2]=vs; rs[(tid>>6)*2+1]=vq; }
    __syncthreads();
    if (tid==0){
        view_part[(n*25+tc)*2]   = rs[0]+rs[2]+rs[4]+rs[6];
        view_part[(n*25+tc)*2+1] = rs[1]+rs[3]+rs[5]+rs[7];
    }
}

// K2a: reduce time partials over 25 chunks -> time_pre; block stat partials.
__global__ __launch_bounds__(256) void k2a_timereduce(
    const float* __restrict__ time_part, float* __restrict__ time_pre,
    float* __restrict__ tstat_part)
{
    int g = blockIdx.x*256 + threadIdx.x;   // [0, 102400)
    int n = g / 1600, r = g % 1600;
    float s = 0.f;
    for (int tc=0; tc<25; tc++) s += time_part[(n*25+tc)*1600 + r];
    time_pre[g] = s;
    float a = s, b = s*s;
    __shared__ float ls[8];
    #pragma unroll
    for (int o=32;o>0;o>>=1){ a += __shfl_down(a,o); b += __shfl_down(b,o); }
    int wid = threadIdx.x >> 6;
    if ((threadIdx.x & 63) == 0){ ls[wid*2] = a; ls[wid*2+1] = b; }
    __syncthreads();
    if (threadIdx.x == 0){
        tstat_part[blockIdx.x*2]   = ls[0]+ls[2]+ls[4]+ls[6];
        tstat_part[blockIdx.x*2+1] = ls[1]+ls[3]+ls[5]+ls[7];
    }
}

// K2b: final scalar BN stats for view/time branches.
__global__ __launch_bounds__(256) void k2b_finstats(
    const float* __restrict__ view_part, const float* __restrict__ tstat_part,
    float* __restrict__ fin)
{
    float acc[4] = {0.f,0.f,0.f,0.f};
    for (int i=threadIdx.x; i<1600; i+=256){ acc[0] += view_part[2*i]; acc[1] += view_part[2*i+1]; }
    for (int i=threadIdx.x; i<400;  i+=256){ acc[2] += tstat_part[2*i]; acc[3] += tstat_part[2*i+1]; }
    __shared__ float ls[4][4];
    int wid = threadIdx.x>>6, lane = threadIdx.x&63;
    #pragma unroll
    for (int j=0;j<4;j++){
        float a = acc[j];
        #pragma unroll
        for (int o=32;o>0;o>>=1) a += __shfl_down(a,o);
        if (lane==0) ls[j][wid] = a;
    }
    __syncthreads();
    if (threadIdx.x==0){
        float VS=ls[0][0]+ls[0][1]+ls[0][2]+ls[0][3];
        float VQ=ls[1][0]+ls[1][1]+ls[1][2]+ls[1][3];
        float TS=ls[2][0]+ls[2][1]+ls[2][2]+ls[2][3];
        float TQ=ls[3][0]+ls[3][1]+ls[3][2]+ls[3][3];
        float vm = VS / 1228800.f;
        float vvar = fmaxf(VQ/1228800.f - vm*vm, 0.f);
        float tm = TS / 102400.f;
        float tvar = fmaxf(TQ/102400.f - tm*tm, 0.f);
        fin[0] = vm; fin[1] = rsqrtf(vvar + EPS);
        fin[2] = tm; fin[3] = rsqrtf(tvar + EPS);
    }
}

// K3: sum2_raw[n,d,l] = sum_ch Ws[d,ch]*F(n, ch*325+l); per-d stat partials.
__global__ __launch_bounds__(256) void k3_conv(
    const float* __restrict__ time_pre, const float* __restrict__ view_pre,
    const float* __restrict__ fin, const float* __restrict__ Ws,
    const float* __restrict__ g_t, const float* __restrict__ be_t,
    const float* __restrict__ g_v, const float* __restrict__ be_v,
    float* __restrict__ sum2_raw, float* __restrict__ chan_part)
{
    const int n = blockIdx.y, lc = blockIdx.x;
    const int tid = threadIdx.x, lane = tid & 63, w = tid >> 6;
    const int l = lc*64 + lane;
    __shared__ float Ft[64][64];    // [ch][l-lane]
    __shared__ float Wst[64][64];   // [ch][d]
    for (int i = tid; i < 4096; i += 256){
        int d = i>>6, ch = i&63;
        Wst[ch][d] = Ws[i];
    }
    const float vm = fin[0], vi = fin[1], tm = fin[2], ti = fin[3];
    const float gt = g_t[0]*ti, bt = be_t[0] - tm*g_t[0]*ti;
    const float gv = g_v[0]*vi, bv = be_v[0] - vm*g_v[0]*vi;
    const bool lval = (l < 325);
    for (int k=0;k<16;k++){
        int ch = w + 4*k;
        float val = 0.f;
        if (lval){
            int idx = ch*325 + l;
            if (idx < 1600) val = hsw(time_pre[n*1600 + idx]*gt + bt);
            else            val = hsw(view_pre[n*19200 + idx - 1600]*gv + bv);
        }
        Ft[ch][lane] = val;
    }
    __syncthreads();
    float acc[16];
    #pragma unroll
    for (int k=0;k<16;k++) acc[k]=0.f;
    const int d0 = w*16;
    #pragma unroll 4
    for (int ch=0; ch<64; ch++){
        float f = Ft[ch][lane];
        #pragma unroll
        for (int dd=0; dd<16; dd++)
            acc[dd] = fmaf(f, Wst[ch][d0+dd], acc[dd]);
    }
    #pragma unroll 1
    for (int dd=0; dd<16; dd++){
        int d = d0 + dd;
        float a = lval ? acc[dd] : 0.f;
        if (lval) sum2_raw[n*20800 + d*325 + l] = a;
        float s = a, q = a*a;
        #pragma unroll
        for (int o=32;o>0;o>>=1){ s += __shfl_down(s,o); q += __shfl_down(q,o); }
        if (lane == 0){
            int b = n*6 + lc;
            chan_part[b*128 + d*2]   = s;
            chan_part[b*128 + d*2+1] = q;
        }
    }
}

// K4: per-channel BN stats.
__global__ void k4_chanstats(const float* __restrict__ chan_part, float* __restrict__ chan_stats)
{
    int d = threadIdx.x;
    float S=0.f, Q=0.f;
    for (int b=0;b<384;b++){ S += chan_part[b*128 + d*2]; Q += chan_part[b*128 + d*2+1]; }
    float m = S/20800.f;
    float var = fmaxf(Q/20800.f - m*m, 0.f);
    chan_stats[d*2] = m;
    chan_stats[d*2+1] = rsqrtf(var + EPS);
}

// K5: xbar[d,l] = mean_n hswish(bn(sum2_raw)).
__global__ __launch_bounds__(256) void k5_xbar(
    const float* __restrict__ sum2_raw, const float* __restrict__ chan_stats,
    const float* __restrict__ g_s, const float* __restrict__ be_s,
    float* __restrict__ xbar)
{
    int g = blockIdx.x*256 + threadIdx.x;
    if (g >= 20800) return;
    int d = g / 325;
    float m = chan_stats[d*2], istd = chan_stats[d*2+1];
    float ga = g_s[d]*istd, bb = be_s[d] - m*ga;
    float acc = 0.f;
    for (int n=0;n<64;n++) acc += hsw(sum2_raw[n*20800 + g]*ga + bb);
    xbar[g] = acc * (1.f/64.f);
}

// K6: gates. l<300 -> x_time output (sigmoid); l>=300 -> scale[v][c]=tanh(sigmoid)+1.
__global__ __launch_bounds__(64) void k6_gates(
    const float* __restrict__ xbar, const float* __restrict__ W2t,
    const float* __restrict__ b2t, const float* __restrict__ W2v,
    const float* __restrict__ b2v, float* __restrict__ out_time,
    float* __restrict__ scale_vc)
{
    int l = blockIdx.x, tid = threadIdx.x;
    __shared__ float xb[64];
    xb[tid] = xbar[tid*325 + l];
    __syncthreads();
    if (l < 300){
        float acc = b2t[tid];
        for (int d=0; d<64; d++) acc += W2t[tid*64+d]*xb[d];
        out_time[tid*300 + l] = sigm(acc);
    } else {
        int v = l - 300;
        float acc = b2v[tid];
        for (int d=0; d<64; d++) acc += W2v[tid*64+d]*xb[d];
        scale_vc[v*64 + tid] = tanhf(sigm(acc)) + 1.f;
    }
}

// K7: y[r][d] = sum_c x_perm[r][c]*scale[r%25][c]*Lw[c][d], MFMA bf16.
__global__ __launch_bounds__(256) void k7_mfma(
    const __hip_bfloat16* __restrict__ x_perm, const float* __restrict__ scale_vc,
    const float* __restrict__ Lw, __hip_bfloat16* __restrict__ y)
{
    __shared__ __hip_bfloat16 As[256*64];
    __shared__ __hip_bfloat16 Bs[64*64];
    const int tid = threadIdx.x;
    const int row0 = blockIdx.x*256;
    for (int i = tid; i < 4096; i += 256){
        int d = i>>6, cc = i&63;
        int sw = (((cc>>3) ^ (d&7))<<3) + (cc&7);
        Bs[d*64 + sw] = __float2bfloat16(Lw[cc*64 + d]);
    }
    for (int i = tid; i < 2048; i += 256){
        int row = i>>3, cc = i&7;
        int grow = row0 + row;
        int v = grow % 25;
        union { float4 f; unsigned short u[8]; } raw;
        raw.f = *reinterpret_cast<const float4*>(x_perm + grow*64 + cc*8);
        const float* sc = scale_vc + v*64 + cc*8;
        __hip_bfloat16 tmp[8];
        #pragma unroll
        for (int j=0;j<8;j++){
            float f = __uint_as_float((unsigned)raw.u[j] << 16);
            tmp[j] = __float2bfloat16(f * sc[j]);
        }
        int swc = (cc ^ (row&7))<<3;
        *reinterpret_cast<float4*>(&As[row*64 + swc]) = *reinterpret_cast<const float4*>(tmp);
    }
    __syncthreads();
    const int wave = tid>>6, lane = tid&63;
    const int lrow = lane&15, lk = lane>>4;
    f32x4 acc[4][4];
    #pragma unroll
    for (int mt=0;mt<4;mt++)
      #pragma unroll
      for (int nt=0;nt<4;nt++) acc[mt][nt] = (f32x4){0.f,0.f,0.f,0.f};
    #pragma unroll
    for (int ks=0;ks<2;ks++){
        bf16x8 a[4], b[4];
        int kc = ks*4 + lk;
        #pragma unroll
        for (int mt=0;mt<4;mt++){
            int row = wave*64 + mt*16 + lrow;
            a[mt] = *reinterpret_cast<const bf16x8*>(&As[row*64 + ((kc ^ (row&7))<<3)]);
        }
        #pragma unroll
        for (int nt=0;nt<4;nt++){
            int d = nt*16 + lrow;
            b[nt] = *reinterpret_cast<const bf16x8*>(&Bs[d*64 + ((kc ^ (d&7))<<3)]);
        }
        #pragma unroll
        for (int mt=0;mt<4;mt++)
          #pragma unroll
          for (int nt=0;nt<4;nt++)
            acc[mt][nt] = __builtin_amdgcn_mfma_f32_16x16x32_bf16(a[mt], b[nt], acc[mt][nt], 0, 0, 0);
    }
    #pragma unroll
    for (int mt=0;mt<4;mt++){
        int growb = row0 + wave*64 + mt*16 + lk*4;
        #pragma unroll
        for (int nt=0;nt<4;nt++){
            int col = nt*16 + lrow;
            #pragma unroll
            for (int j=0;j<4;j++)
                y[(growb + j)*64 + col] = __float2bfloat16(acc[mt][nt][j]);
        }
    }
}

// K8 v2: 1200 blocks x 16 rows; each thread owns 4-col chunks (uint2 loads).
__global__ __launch_bounds__(256) void k8_colpart(
    const __hip_bfloat16* __restrict__ y, float* __restrict__ col_part)
{
    const int b = blockIdx.x, tid = threadIdx.x;
    const int r0 = b*16;
    const bool has2 = tid < 144;
    float s0[4]={0.f,0.f,0.f,0.f}, q0[4]={0.f,0.f,0.f,0.f};
    float s1[4]={0.f,0.f,0.f,0.f}, q1[4]={0.f,0.f,0.f,0.f};
    for (int r=r0; r<r0+16; r++){
        const __hip_bfloat16* yr = y + r*1600;
        uint2 u = *reinterpret_cast<const uint2*>(yr + tid*4);
        float a0 = __uint_as_float(u.x << 16);
        float a1 = __uint_as_float(u.x & 0xffff0000u);
        float a2 = __uint_as_float(u.y << 16);
        float a3 = __uint_as_float(u.y & 0xffff0000u);
        s0[0]+=a0; q0[0]+=a0*a0; s0[1]+=a1; q0[1]+=a1*a1;
        s0[2]+=a2; q0[2]+=a2*a2; s0[3]+=a3; q0[3]+=a3*a3;
        if (has2){
            uint2 w = *reinterpret_cast<const uint2*>(yr + (tid+256)*4);
            float b0 = __uint_as_float(w.x << 16);
            float b1 = __uint_as_float(w.x & 0xffff0000u);
            float b2 = __uint_as_float(w.y << 16);
            float b3 = __uint_as_float(w.y & 0xffff0000u);
            s1[0]+=b0; q1[0]+=b0*b0; s1[1]+=b1; q1[1]+=b1*b1;
            s1[2]+=b2; q1[2]+=b2*b2; s1[3]+=b3; q1[3]+=b3*b3;
        }
    }
    float* cp = col_part + (tid*1200 + b)*8;
    #pragma unroll
    for (int e=0;e<4;e++){ cp[e] = s0[e]; cp[4+e] = q0[e]; }
    if (has2){
        float* cp2 = col_part + ((tid+256)*1200 + b)*8;
        #pragma unroll
        for (int e=0;e<4;e++){ cp2[e] = s1[e]; cp2[4+e] = q1[e]; }
    }
}

// K8b v2: one block per 4-col chunk; reduce 1200 block-partials.
__global__ __launch_bounds__(256) void k8b_colstats(
    const float* __restrict__ col_part, float* __restrict__ col_stats)
{
    const int j = blockIdx.x, tid = threadIdx.x;
    float acc[8] = {0.f,0.f,0.f,0.f,0.f,0.f,0.f,0.f};
    for (int b = tid; b < 1200; b += 256){
        const float* cp = col_part + (j*1200 + b)*8;
        float4 x0 = *reinterpret_cast<const float4*>(cp);
        float4 x1 = *reinterpret_cast<const float4*>(cp+4);
        acc[0]+=x0.x; acc[1]+=x0.y; acc[2]+=x0.z; acc[3]+=x0.w;
        acc[4]+=x1.x; acc[5]+=x1.y; acc[6]+=x1.z; acc[7]+=x1.w;
    }
    #pragma unroll
    for (int e=0;e<8;e++){
        #pragma unroll
        for (int o=32;o>0;o>>=1) acc[e] += __shfl_down(acc[e], o);
    }
    __shared__ float red[4][8];
    if ((tid&63)==0){
        #pragma unroll
        for (int e=0;e<8;e++) red[tid>>6][e] = acc[e];
    }
    __syncthreads();
    if (tid < 4){
        float S = red[0][tid]+red[1][tid]+red[2][tid]+red[3][tid];
        float Q = red[0][4+tid]+red[1][4+tid]+red[2][4+tid]+red[3][4+tid];
        float m = S/19200.f;
        float var = fmaxf(Q/19200.f - m*m, 0.f);
        int col = j*4 + tid;
        col_stats[col*2]   = m;
        col_stats[col*2+1] = rsqrtf(var + EPS);
    }
}

// K8c: colAB[s] = (A, B) for s = shift_out[j] — INVERSE-permuted so k9's
// staging reads it coalesced by column index.
__global__ __launch_bounds__(256) void k8c_jparams(
    const int* __restrict__ shift_out, const float* __restrict__ col_stats,
    const float* __restrict__ g_bn, const float* __restrict__ be_bn,
    float2* __restrict__ colAB)
{
    int j = blockIdx.x*256 + threadIdx.x;
    if (j >= 1600) return;
    int s = shift_out[j];
    float m = col_stats[s*2], istd = col_stats[s*2+1];
    float A = istd * g_bn[j];
    float B = be_bn[j] - m*A;
    colAB[s] = make_float2(A, B);
}

// K9 v3: permute-at-staging. Stage 4 contiguous y rows, apply BN affine
// (colAB coalesced), write pre-permuted f32 ysp[d][tt*25+v] (v=(m+d)%25).
// Main loop: contiguous float4 LDS read + float4 x0 read + relu + float4 store.
__global__ __launch_bounds__(256) void k9_final(
    const float* __restrict__ x0, const __hip_bfloat16* __restrict__ y,
    const float2* __restrict__ colAB, float* __restrict__ out)
{
    const int tc = blockIdx.x, n = blockIdx.y, t0 = tc*4;
    const int tid = threadIdx.x;
    __shared__ float ysp[64*104];     // [d][rem], rem = tt*25+v, pad 100->104
    const __hip_bfloat16* yb = y + (n*300 + t0)*1600;
    for (int i = tid; i < 1600; i += 256){
        int tt = i / 400;
        int q  = i - tt*400;
        int col0 = q*4;
        uint2 u = *reinterpret_cast<const uint2*>(yb + tt*1600 + col0);
        float4 ab01 = *reinterpret_cast<const float4*>(&colAB[col0]);
        float4 ab23 = *reinterpret_cast<const float4*>(&colAB[col0+2]);
        float yv0 = __uint_as_float(u.x << 16);
        float yv1 = __uint_as_float(u.x & 0xffff0000u);
        float yv2 = __uint_as_float(u.y << 16);
        float yv3 = __uint_as_float(u.y & 0xffff0000u);
        int m = col0 >> 6, d0 = col0 & 63;
        int vv = (m + d0) % 25;
        float vals[4] = { fmaf(yv0, ab01.x, ab01.y), fmaf(yv1, ab01.z, ab01.w),
                          fmaf(yv2, ab23.x, ab23.y), fmaf(yv3, ab23.z, ab23.w) };
        int base = tt*25;
        #pragma unroll
        for (int j=0;j<4;j++){
            int v = vv + j; if (v >= 25) v -= 25;
            ysp[(d0+j)*104 + base + v] = vals[j];
        }
    }
    __syncthreads();
    const int base_x = n*480000 + tc*100;
    for (int i = tid; i < 1600; i += 256){
        int d = i/25, ch = i - d*25;
        int rem0 = ch*4;
        int gidx = base_x + d*7500 + rem0;
        float4 xv = *reinterpret_cast<const float4*>(x0 + gidx);
        float4 yv = *reinterpret_cast<const float4*>(&ysp[d*104 + rem0]);
        float4 ov;
        ov.x = fmaxf(yv.x + xv.x, 0.f);
        ov.y = fmaxf(yv.y + xv.y, 0.f);
        ov.z = fmaxf(yv.z + xv.z, 0.f);
        ov.w = fmaxf(yv.w + xv.w, 0.f);
        *reinterpret_cast<float4*>(out + gidx) = ov;
    }
}

extern "C" void kernel_launch(void* const* d_in, const int* in_sizes, int n_in,
                              void* d_out, int out_size, void* d_ws, size_t ws_size,
                              hipStream_t stream)
{
    const float* x0       = (const float*)d_in[0];
    const int*   shift_in = (const int*)d_in[1];
    const int*   shift_out= (const int*)d_in[2];
    const float* Wv       = (const float*)d_in[3];
    const float* g_v      = (const float*)d_in[5];
    const float* be_v     = (const float*)d_in[6];
    const float* Wt       = (const float*)d_in[7];
    const float* g_t      = (const float*)d_in[9];
    const float* be_t     = (const float*)d_in[10];
    const float* Ws       = (const float*)d_in[11];
    const float* g_s      = (const float*)d_in[13];
    const float* be_s     = (const float*)d_in[14];
    const float* W2t      = (const float*)d_in[15];
    const float* b2t      = (const float*)d_in[16];
    const float* W2v      = (const float*)d_in[17];
    const float* b2v      = (const float*)d_in[18];
    const float* Lw       = (const float*)d_in[19];
    const float* g_bn     = (const float*)d_in[21];
    const float* be_bn    = (const float*)d_in[22];

    float* ws = (float*)d_ws;
    float* view_pre  = ws;                  // 1,228,800  (dead after k3)
    float* time_part = ws + 1228800;        // 2,560,000  (dead after k2a)
    float* time_pre  = ws + 3788800;        //   102,400  (dead after k3)
    float* view_part = ws + 3891200;        //     3,200  (dead after k2b)
    float* tstat_part= ws + 3894400;        //       800
    float* fin       = ws + 3895200;        //         8
    float* sum2_raw  = ws + 3895208;        // 1,331,200
    float* chan_part = ws + 5226408;        //    49,152
    float* chan_stats= ws + 5275560;        //       128
    float* xbar      = ws + 5275688;        //    20,800
    float* scale_vc  = ws + 5296488;        //     1,600
    float* col_part  = ws;                  // 3,840,000 floats — ALIASES view_pre..time_pre (dead by k8)
    float* col_stats = ws + 5810088;        //     3,200
    float2* colAB    = (float2*)(ws + 5813288); // 1,600 float2
    __hip_bfloat16* x_perm = (__hip_bfloat16*)(ws + 5819688); // 30,720,000 bf16
    __hip_bfloat16* y = x_perm;             // in-place alias (row-wise 1:1)

    float* out      = (float*)d_out;
    float* out_time = out + 30720000;

    k1_viewtime   <<<dim3(25,64), 256, 0, stream>>>(x0, shift_in, Wv, Wt, view_pre, time_part, view_part, x_perm);
    k2a_timereduce<<<400, 256, 0, stream>>>(time_part, time_pre, tstat_part);
    k2b_finstats  <<<1, 256, 0, stream>>>(view_part, tstat_part, fin);
    k3_conv       <<<dim3(6,64), 256, 0, stream>>>(time_pre, view_pre, fin, Ws, g_t, be_t, g_v, be_v, sum2_raw, chan_part);
    k4_chanstats  <<<1, 64, 0, stream>>>(chan_part, chan_stats);
    k5_xbar       <<<82, 256, 0, stream>>>(sum2_raw, chan_stats, g_s, be_s, xbar);
    k6_gates      <<<325, 64, 0, stream>>>(xbar, W2t, b2t, W2v, b2v, out_time, scale_vc);
    k7_mfma       <<<1875, 256, 0, stream>>>(x_perm, scale_vc, Lw, y);
    k8_colpart    <<<1200, 256, 0, stream>>>(y, col_part);
    k8b_colstats  <<<400, 256, 0, stream>>>(col_part, col_stats);
    k8c_jparams   <<<7, 256, 0, stream>>>(shift_out, col_stats, g_bn, be_bn, colAB);
    k9_final      <<<dim3(75,64), 256, 0, stream>>>(x0, y, colAB, out);
}